// Round 11
// baseline (576.776 us; speedup 1.0000x reference)
//
#include <hip/hip_runtime.h>
#include <hip/hip_bf16.h>

typedef __hip_bfloat16 bf16;

#define B_ 2
#define T_ 1024
#define C_ 1024
#define H_ 16
#define N_ 64

using short4v = __attribute__((ext_vector_type(4))) short;
using short8 = __attribute__((ext_vector_type(8))) short;
using f32x4 = __attribute__((ext_vector_type(4))) float;

__device__ __forceinline__ float bs2f(short s) {
  return __uint_as_float(((unsigned int)(unsigned short)s) << 16);
}
__device__ __forceinline__ bf16 f2bf(float f) { return __float2bfloat16(f); }
__device__ __forceinline__ short bfbits(float f) {
  bf16 h = __float2bfloat16(f);
  return *reinterpret_cast<short*>(&h);
}
__device__ __forceinline__ float sigmoidf_(float x) { return 1.0f / (1.0f + expf(-x)); }
__device__ __forceinline__ float softplusf_(float x) {
  return fmaxf(x, 0.0f) + log1pf(expf(-fabsf(x)));
}
// Full 16-lane-row sum, all lanes receive the result. Pure-VALU DPP.
__device__ __forceinline__ float qsum16(float x) {
  int a = __builtin_amdgcn_update_dpp(0, __float_as_int(x), 0xB1, 0xF, 0xF, true);
  x += __int_as_float(a);
  int b = __builtin_amdgcn_update_dpp(0, __float_as_int(x), 0x4E, 0xF, 0xF, true);
  x += __int_as_float(b);
  int c = __builtin_amdgcn_update_dpp(0, __float_as_int(x), 0x124, 0xF, 0xF, true);
  x += __int_as_float(c);
  int d = __builtin_amdgcn_update_dpp(0, __float_as_int(x), 0x128, 0xF, 0xF, true);
  x += __int_as_float(d);
  return x;
}
// Two interleaved 16-lane-row sums (overlaps token t's sab chain with token
// t-1's y chain; see scan_kernel comment).
__device__ __forceinline__ void qsum16x2(float& x, float& y) {
  int a0 = __builtin_amdgcn_update_dpp(0, __float_as_int(x), 0xB1, 0xF, 0xF, true);
  int b0 = __builtin_amdgcn_update_dpp(0, __float_as_int(y), 0xB1, 0xF, 0xF, true);
  x += __int_as_float(a0); y += __int_as_float(b0);
  int a1 = __builtin_amdgcn_update_dpp(0, __float_as_int(x), 0x4E, 0xF, 0xF, true);
  int b1 = __builtin_amdgcn_update_dpp(0, __float_as_int(y), 0x4E, 0xF, 0xF, true);
  x += __int_as_float(a1); y += __int_as_float(b1);
  int a2 = __builtin_amdgcn_update_dpp(0, __float_as_int(x), 0x124, 0xF, 0xF, true);
  int b2 = __builtin_amdgcn_update_dpp(0, __float_as_int(y), 0x124, 0xF, 0xF, true);
  x += __int_as_float(a2); y += __int_as_float(b2);
  int a3 = __builtin_amdgcn_update_dpp(0, __float_as_int(x), 0x128, 0xF, 0xF, true);
  int b3 = __builtin_amdgcn_update_dpp(0, __float_as_int(y), 0x128, 0xF, 0xF, true);
  x += __int_as_float(a3); y += __int_as_float(b3);
}

// ---------------- K0: cvt + expansions + mix-GEMM, ONE launch ---------------
// Blocks 0..5759: weight fp32->bf16 conversions + tmw2e/w2e5 expansions.
// Blocks 5760..5791: the mix GEMM (A = token-shifted x on the fly; W staged
// directly from f32 tmw1 -> no dependency on the cvt blocks, so they can
// share one launch).
__global__ __launch_bounds__(256) void cvt_mix_kernel(
    const float* __restrict__ s0, const float* __restrict__ s1,
    const float* __restrict__ s2, const float* __restrict__ s3,
    const float* __restrict__ s4, const float* __restrict__ s5,
    const float* __restrict__ s6,
    bf16* __restrict__ d0, bf16* __restrict__ d1, bf16* __restrict__ d2w,
    bf16* __restrict__ d3, bf16* __restrict__ d4, bf16* __restrict__ d5,
    bf16* __restrict__ d6,
    const float* __restrict__ tkw1, const float* __restrict__ mkw1,
    const float* __restrict__ tdw1, const float* __restrict__ taw1,
    const float* __restrict__ maw1,
    bf16* __restrict__ wsk, bf16* __restrict__ wswa,
    const float* __restrict__ tmw2, const float* __restrict__ tdw2,
    const float* __restrict__ tkw2, const float* __restrict__ taw2,
    const float* __restrict__ maw2, const float* __restrict__ mkw2,
    bf16* __restrict__ tmw2e, bf16* __restrict__ w2e5,
    const float* __restrict__ x, const float* __restrict__ tmx,
    bf16* __restrict__ mixb) {
  long bidx = blockIdx.x;
  if (bidx >= 5760) {                     // -------- mix GEMM blocks --------
    __shared__ __align__(16) bf16 As[128][72];
    __shared__ __align__(16) bf16 Ws[64][72];
    const int K = 1024;
    int mb = (int)(bidx - 5760);
    int n0 = (mb & 1) << 6;
    int m0 = (mb >> 1) << 7;
    int tid = threadIdx.x;
    int arow = tid >> 1, acol = (tid & 1) << 5;
    int wrow = tid >> 2, wcol = (tid & 3) << 4;
    int wv = tid >> 6, lane = tid & 63;
    int fr = lane & 15, fq = lane >> 4;
    int grow = m0 + arow;
    int t = grow & (T_ - 1);
    const float* xp = x + (long)grow * C_ + acol;
    const float* Wp = s0 + (long)(n0 + wrow) * K + wcol;  // raw f32 tmw1
    f32x4 a00 = {0.f, 0.f, 0.f, 0.f};
    f32x4 a01 = a00, a02 = a00, a03 = a00, a10 = a00, a11 = a00, a12 = a00, a13 = a00;
    for (int k0 = 0; k0 < K; k0 += 64) {
#pragma unroll
      for (int jj = 0; jj < 4; jj++) {
        int co = k0 + (jj << 3);
        float4 c0 = *(const float4*)(xp + co);
        float4 c1 = *(const float4*)(xp + co + 4);
        float4 q0 = {0.f, 0.f, 0.f, 0.f}, q1 = q0;
        if (t > 0) {
          q0 = *(const float4*)(xp + co - C_);
          q1 = *(const float4*)(xp + co + 4 - C_);
        }
        float4 m0v = *(const float4*)(tmx + co + acol);
        float4 m1v = *(const float4*)(tmx + co + acol + 4);
        short8 sv;
        sv[0] = bfbits(fmaf(q0.x - c0.x, m0v.x, c0.x));
        sv[1] = bfbits(fmaf(q0.y - c0.y, m0v.y, c0.y));
        sv[2] = bfbits(fmaf(q0.z - c0.z, m0v.z, c0.z));
        sv[3] = bfbits(fmaf(q0.w - c0.w, m0v.w, c0.w));
        sv[4] = bfbits(fmaf(q1.x - c1.x, m1v.x, c1.x));
        sv[5] = bfbits(fmaf(q1.y - c1.y, m1v.y, c1.y));
        sv[6] = bfbits(fmaf(q1.z - c1.z, m1v.z, c1.z));
        sv[7] = bfbits(fmaf(q1.w - c1.w, m1v.w, c1.w));
        *(short8*)&As[arow][acol + (jj << 3)] = sv;
      }
      {
        float4 w0 = *(const float4*)(Wp + k0);
        float4 w1 = *(const float4*)(Wp + k0 + 4);
        float4 w2 = *(const float4*)(Wp + k0 + 8);
        float4 w3 = *(const float4*)(Wp + k0 + 12);
        short8 wv0, wv1;
        wv0[0] = bfbits(w0.x); wv0[1] = bfbits(w0.y); wv0[2] = bfbits(w0.z); wv0[3] = bfbits(w0.w);
        wv0[4] = bfbits(w1.x); wv0[5] = bfbits(w1.y); wv0[6] = bfbits(w1.z); wv0[7] = bfbits(w1.w);
        wv1[0] = bfbits(w2.x); wv1[1] = bfbits(w2.y); wv1[2] = bfbits(w2.z); wv1[3] = bfbits(w2.w);
        wv1[4] = bfbits(w3.x); wv1[5] = bfbits(w3.y); wv1[6] = bfbits(w3.z); wv1[7] = bfbits(w3.w);
        *(short8*)&Ws[wrow][wcol] = wv0;
        *(short8*)&Ws[wrow][wcol + 8] = wv1;
      }
      __syncthreads();
#pragma unroll
      for (int kk = 0; kk < 2; kk++) {
        int ko = (fq << 3) + (kk << 5);
        short8 af0 = *(const short8*)&As[(wv << 5) + fr][ko];
        short8 af1 = *(const short8*)&As[(wv << 5) + 16 + fr][ko];
        short8 b0 = *(const short8*)&Ws[fr][ko];
        short8 b1 = *(const short8*)&Ws[16 + fr][ko];
        short8 b2 = *(const short8*)&Ws[32 + fr][ko];
        short8 b3 = *(const short8*)&Ws[48 + fr][ko];
        a00 = __builtin_amdgcn_mfma_f32_16x16x32_bf16(af0, b0, a00, 0, 0, 0);
        a01 = __builtin_amdgcn_mfma_f32_16x16x32_bf16(af0, b1, a01, 0, 0, 0);
        a02 = __builtin_amdgcn_mfma_f32_16x16x32_bf16(af0, b2, a02, 0, 0, 0);
        a03 = __builtin_amdgcn_mfma_f32_16x16x32_bf16(af0, b3, a03, 0, 0, 0);
        a10 = __builtin_amdgcn_mfma_f32_16x16x32_bf16(af1, b0, a10, 0, 0, 0);
        a11 = __builtin_amdgcn_mfma_f32_16x16x32_bf16(af1, b1, a11, 0, 0, 0);
        a12 = __builtin_amdgcn_mfma_f32_16x16x32_bf16(af1, b2, a12, 0, 0, 0);
        a13 = __builtin_amdgcn_mfma_f32_16x16x32_bf16(af1, b3, a13, 0, 0, 0);
      }
      __syncthreads();
    }
    const int Nz = 128;
    int ocol = n0 + fr;
    int orow0 = m0 + (wv << 5) + (fq << 2);
#define WRM(accv, mf, nt) { int col = ocol + ((nt) << 4); \
    _Pragma("unroll") for (int r = 0; r < 4; r++) { \
      long oi = (long)(orow0 + ((mf) << 4) + r) * Nz + col; \
      mixb[oi] = f2bf(tanhf(accv[r])); } }
    WRM(a00, 0, 0) WRM(a01, 0, 1) WRM(a02, 0, 2) WRM(a03, 0, 3)
    WRM(a10, 1, 0) WRM(a11, 1, 1) WRM(a12, 1, 2) WRM(a13, 1, 3)
#undef WRM
    return;
  }
  const float* s; bf16* d; long off;
  if (bidx < 4480) {                      // big weights
    long i4 = bidx * 256 + threadIdx.x;
    if (i4 < 32768) { s = s0; d = d0; off = i4; }
    else if (i4 < 294912) { s = s1; d = d1; off = i4 - 32768; }
    else if (i4 < 327680) { s = s2; d = d2w; off = i4 - 294912; }
    else if (i4 < 360448) { s = s3; d = d3; off = i4 - 327680; }
    else if (i4 < 622592) { s = s4; d = d4; off = i4 - 360448; }
    else if (i4 < 884736) { s = s5; d = d5; off = i4 - 622592; }
    else { s = s6; d = d6; off = i4 - 884736; }
  } else if (bidx < 4608) {               // LoRA-1 packs
    long i4 = (bidx - 4480) * 256 + threadIdx.x;  // < 32768
    long so, dof;
    if (i4 < 4096) { s = tkw1; so = i4; d = wsk; dof = i4; }
    else if (i4 < 8192) { s = mkw1; so = i4 - 4096; d = wsk; dof = i4; }
    else if (i4 < 24576) { s = tdw1; so = i4 - 8192; d = wswa; dof = i4 - 8192; }
    else if (i4 < 28672) { s = taw1; so = i4 - 24576; d = wswa; dof = i4 - 8192; }
    else { s = maw1; so = i4 - 28672; d = wswa; dof = i4 - 8192; }
    float4 v = *(const float4*)(s + so * 4);
    d[dof * 4 + 0] = f2bf(v.x); d[dof * 4 + 1] = f2bf(v.y);
    d[dof * 4 + 2] = f2bf(v.z); d[dof * 4 + 3] = f2bf(v.w);
    return;
  } else if (bidx < 5120) {               // tmw2e expansion (4096x128)
    long i4 = (bidx - 4608) * 256 + threadIdx.x;  // < 131072
    long n = i4 >> 5;
    int k0 = (int)(i4 & 31) << 2;
    int f = (int)(n >> 10);
    float4 v = {0.f, 0.f, 0.f, 0.f};
    if ((k0 >> 5) == f) v = *(const float4*)(tmw2 + n * 32 + (k0 & 31));
    tmw2e[i4 * 4 + 0] = f2bf(v.x);
    tmw2e[i4 * 4 + 1] = f2bf(v.y);
    tmw2e[i4 * 4 + 2] = f2bf(v.z);
    tmw2e[i4 * 4 + 3] = f2bf(v.w);
    return;
  } else {                                // w2e5 expansion (5120x128)
    long i4 = (bidx - 5120) * 256 + threadIdx.x;  // < 163840
    long rowi = i4 >> 5;                  // 0..5119
    int k0 = (int)(i4 & 31) << 2;         // 0..124
    int j = (int)(rowi >> 10);
    int c = (int)(rowi & 1023);
    float4 v = {0.f, 0.f, 0.f, 0.f};
    if (j == 0) { if (k0 < 64) v = *(const float4*)(tdw2 + c * 64 + k0); }
    else if (j == 1) { if (k0 >= 64 && k0 < 80) v = *(const float4*)(taw2 + c * 16 + (k0 - 64)); }
    else if (j == 2) { if (k0 >= 80 && k0 < 96) v = *(const float4*)(maw2 + c * 16 + (k0 - 80)); }
    else if (j == 3) { if (k0 >= 96 && k0 < 112) v = *(const float4*)(tkw2 + c * 16 + (k0 - 96)); }
    else { if (k0 >= 112) v = *(const float4*)(mkw2 + c * 16 + (k0 - 112)); }
    w2e5[i4 * 4 + 0] = f2bf(v.x);
    w2e5[i4 * 4 + 1] = f2bf(v.y);
    w2e5[i4 * 4 + 2] = f2bf(v.z);
    w2e5[i4 * 4 + 3] = f2bf(v.w);
    return;
  }
  float4 v = *(const float4*)(s + off * 4);
  d[off * 4 + 0] = f2bf(v.x);
  d[off * 4 + 1] = f2bf(v.y);
  d[off * 4 + 2] = f2bf(v.z);
  d[off * 4 + 3] = f2bf(v.w);
}

// ---------------- Batched MFMA GEMM: C[z] = A[z] * W[z]^T -------------------
// 128x64 tile, 4 waves x (2 M-frags x 4 N-frags). ldc/coff let several GEMMs
// write column slices of one combined buffer (out12).
struct GemmBatch {
  const bf16* A[6]; const bf16* W[6];
  float* Cf[6]; bf16* Cb[6];
  int N[6]; int actN[6]; int ldc[6]; int coff[6];
};

__global__ __launch_bounds__(256) void gemm_batch_kernel(GemmBatch gb, int K) {
  __shared__ __align__(16) bf16 As[128][72];
  __shared__ __align__(16) bf16 Ws[64][72];
  int z = blockIdx.z;
  int Nz = gb.N[z];
  int n0 = blockIdx.x << 6;
  if (n0 >= Nz) return;
  int m0 = blockIdx.y << 7;
  int actN = gb.actN[z];
  int ldc = gb.ldc[z], coff = gb.coff[z];
  const bf16* A = gb.A[z];
  const bf16* W = gb.W[z];
  float* Cf = gb.Cf[z];
  bf16* Cb = gb.Cb[z];
  int tid = threadIdx.x;
  int arow = tid >> 1, acol = (tid & 1) << 5;
  int wrow = tid >> 2, wcol = (tid & 3) << 4;
  int wv = tid >> 6, lane = tid & 63;
  int fr = lane & 15, fq = lane >> 4;
  bool wok = (n0 + wrow) < Nz;
  const bf16* Ap = A + (long)(m0 + arow) * K + acol;
  const bf16* Wp = W + (long)(n0 + wrow) * K + wcol;
  short8 zz = {0, 0, 0, 0, 0, 0, 0, 0};
  f32x4 a00 = {0.f, 0.f, 0.f, 0.f};
  f32x4 a01 = a00, a02 = a00, a03 = a00, a10 = a00, a11 = a00, a12 = a00, a13 = a00;
  for (int k0 = 0; k0 < K; k0 += 64) {
    *(short8*)&As[arow][acol] = *(const short8*)(Ap + k0);
    *(short8*)&As[arow][acol + 8] = *(const short8*)(Ap + k0 + 8);
    *(short8*)&As[arow][acol + 16] = *(const short8*)(Ap + k0 + 16);
    *(short8*)&As[arow][acol + 24] = *(const short8*)(Ap + k0 + 24);
    *(short8*)&Ws[wrow][wcol] = wok ? *(const short8*)(Wp + k0) : zz;
    *(short8*)&Ws[wrow][wcol + 8] = wok ? *(const short8*)(Wp + k0 + 8) : zz;
    __syncthreads();
#pragma unroll
    for (int kk = 0; kk < 2; kk++) {
      int ko = (fq << 3) + (kk << 5);
      short8 af0 = *(const short8*)&As[(wv << 5) + fr][ko];
      short8 af1 = *(const short8*)&As[(wv << 5) + 16 + fr][ko];
      short8 b0 = *(const short8*)&Ws[fr][ko];
      short8 b1 = *(const short8*)&Ws[16 + fr][ko];
      short8 b2 = *(const short8*)&Ws[32 + fr][ko];
      short8 b3 = *(const short8*)&Ws[48 + fr][ko];
      a00 = __builtin_amdgcn_mfma_f32_16x16x32_bf16(af0, b0, a00, 0, 0, 0);
      a01 = __builtin_amdgcn_mfma_f32_16x16x32_bf16(af0, b1, a01, 0, 0, 0);
      a02 = __builtin_amdgcn_mfma_f32_16x16x32_bf16(af0, b2, a02, 0, 0, 0);
      a03 = __builtin_amdgcn_mfma_f32_16x16x32_bf16(af0, b3, a03, 0, 0, 0);
      a10 = __builtin_amdgcn_mfma_f32_16x16x32_bf16(af1, b0, a10, 0, 0, 0);
      a11 = __builtin_amdgcn_mfma_f32_16x16x32_bf16(af1, b1, a11, 0, 0, 0);
      a12 = __builtin_amdgcn_mfma_f32_16x16x32_bf16(af1, b2, a12, 0, 0, 0);
      a13 = __builtin_amdgcn_mfma_f32_16x16x32_bf16(af1, b3, a13, 0, 0, 0);
    }
    __syncthreads();
  }
  int ocol = n0 + fr;
  int orow0 = m0 + (wv << 5) + (fq << 2);
#define WRB(accv, mf, nt) { int col = ocol + ((nt) << 4); if (col < Nz) { \
    _Pragma("unroll") for (int r = 0; r < 4; r++) { \
      float vvv = accv[r]; if (col < actN) vvv = tanhf(vvv); \
      long oi = (long)(orow0 + ((mf) << 4) + r) * ldc + coff + col; \
      if (Cb) Cb[oi] = f2bf(vvv); else Cf[oi] = vvv; } } }
  WRB(a00, 0, 0) WRB(a01, 0, 1) WRB(a02, 0, 2) WRB(a03, 0, 3)
  WRB(a10, 1, 0) WRB(a11, 1, 1) WRB(a12, 1, 2) WRB(a13, 1, 3)
#undef WRB
}

// ---------------- deltas GEMM with fused mix-apply epilogue -----------------
__global__ __launch_bounds__(256) void gemm_mixapply_kernel(
    const bf16* __restrict__ A, const bf16* __restrict__ W,
    const float* __restrict__ x, const float* __restrict__ tmaa,
    bf16* __restrict__ xrg, bf16* __restrict__ xwa,
    bf16* __restrict__ xk, bf16* __restrict__ xv) {
  __shared__ __align__(16) bf16 As[128][72];
  __shared__ __align__(16) bf16 Ws[64][72];
  const int K = 128;
  int n0 = blockIdx.x << 6;   // 0..4032
  int m0 = blockIdx.y << 7;
  int tid = threadIdx.x;
  int arow = tid >> 1, acol = (tid & 1) << 5;
  int wrow = tid >> 2, wcol = (tid & 3) << 4;
  int wv = tid >> 6, lane = tid & 63;
  int fr = lane & 15, fq = lane >> 4;
  const bf16* Ap = A + (long)(m0 + arow) * K + acol;
  const bf16* Wp = W + (long)(n0 + wrow) * K + wcol;
  f32x4 a00 = {0.f, 0.f, 0.f, 0.f};
  f32x4 a01 = a00, a02 = a00, a03 = a00, a10 = a00, a11 = a00, a12 = a00, a13 = a00;
  for (int k0 = 0; k0 < K; k0 += 64) {
    *(short8*)&As[arow][acol] = *(const short8*)(Ap + k0);
    *(short8*)&As[arow][acol + 8] = *(const short8*)(Ap + k0 + 8);
    *(short8*)&As[arow][acol + 16] = *(const short8*)(Ap + k0 + 16);
    *(short8*)&As[arow][acol + 24] = *(const short8*)(Ap + k0 + 24);
    *(short8*)&Ws[wrow][wcol] = *(const short8*)(Wp + k0);
    *(short8*)&Ws[wrow][wcol + 8] = *(const short8*)(Wp + k0 + 8);
    __syncthreads();
#pragma unroll
    for (int kk = 0; kk < 2; kk++) {
      int ko = (fq << 3) + (kk << 5);
      short8 af0 = *(const short8*)&As[(wv << 5) + fr][ko];
      short8 af1 = *(const short8*)&As[(wv << 5) + 16 + fr][ko];
      short8 b0 = *(const short8*)&Ws[fr][ko];
      short8 b1 = *(const short8*)&Ws[16 + fr][ko];
      short8 b2 = *(const short8*)&Ws[32 + fr][ko];
      short8 b3 = *(const short8*)&Ws[48 + fr][ko];
      a00 = __builtin_amdgcn_mfma_f32_16x16x32_bf16(af0, b0, a00, 0, 0, 0);
      a01 = __builtin_amdgcn_mfma_f32_16x16x32_bf16(af0, b1, a01, 0, 0, 0);
      a02 = __builtin_amdgcn_mfma_f32_16x16x32_bf16(af0, b2, a02, 0, 0, 0);
      a03 = __builtin_amdgcn_mfma_f32_16x16x32_bf16(af0, b3, a03, 0, 0, 0);
      a10 = __builtin_amdgcn_mfma_f32_16x16x32_bf16(af1, b0, a10, 0, 0, 0);
      a11 = __builtin_amdgcn_mfma_f32_16x16x32_bf16(af1, b1, a11, 0, 0, 0);
      a12 = __builtin_amdgcn_mfma_f32_16x16x32_bf16(af1, b2, a12, 0, 0, 0);
      a13 = __builtin_amdgcn_mfma_f32_16x16x32_bf16(af1, b3, a13, 0, 0, 0);
    }
    __syncthreads();
  }
  int f = n0 >> 10;
  int c0 = n0 & 1023;
  bf16* outp = (f == 0) ? xrg : (f == 1) ? xwa : (f == 2) ? xk : xv;
  int ocol = c0 + fr;
  int orow0 = m0 + (wv << 5) + (fq << 2);
#define WRA(accv, mf, nt) { int cc = ocol + ((nt) << 4); \
    float ta = tmaa[(f << 10) + cc]; \
    _Pragma("unroll") for (int r = 0; r < 4; r++) { \
      int row = orow0 + ((mf) << 4) + r; \
      int t = row & (T_ - 1); \
      long xo = (long)row * C_ + cc; \
      float xb = x[xo]; \
      float xq = (t > 0) ? x[xo - C_] : 0.0f; \
      outp[xo] = f2bf(fmaf(xq - xb, ta + accv[r], xb)); } }
  WRA(a00, 0, 0) WRA(a01, 0, 1) WRA(a02, 0, 2) WRA(a03, 0, 3)
  WRA(a10, 1, 0) WRA(a11, 1, 1) WRA(a12, 1, 2) WRA(a13, 1, 3)
#undef WRA
}

// ---------------- K6: RWKV-7 scan + fused fuse2 (staging-side) --------------
// R3 structure (dbuf LDS, 3-set rotating register pipeline, sched_barrier) +
// R7 y-pipeline. R10: fuse2 folded into the STAGING path -- loadc reads
// {kraw, 5 d2 slices, r, v}; stage() computes ew/kfin/kkn/bb in registers
// (per-head sumsq reduce = the existing 16-lane DPP row: the 16 staging lanes
// of a token ARE one DPP row) and writes the 6 LDS streams + kfin to global
// (gnout needs it). The scan is latency-bound (VALUBusy 21%), so the ~30
// transcendentals/chunk ride in idle issue slots. Kills the fuse2 launch and
// the ew/kkn/bbo memory roundtrips.
#define SCHUNK 16
#define NCHUNK (T_ / SCHUNK)
__global__ __launch_bounds__(256, 1) void scan_kernel(
    const float* __restrict__ rB, const float* __restrict__ vvB,
    const float* __restrict__ krawB, const float* __restrict__ d2B,
    const float* __restrict__ tdec, const float* __restrict__ taa,
    const float* __restrict__ tma, const float* __restrict__ tmk,
    float* __restrict__ yB, float* __restrict__ kfB) {
  __shared__ __align__(16) float lds[2][6][SCHUNK * 64];
  int bid = blockIdx.x;          // 0..127
  int bh = bid >> 2, rg = bid & 3;
  int b = bh >> 4, h = bh & 15;
  int tid = threadIdx.x;
  int wave = tid >> 6, lane = tid & 63;
  int g = lane >> 4, q = lane & 15;
  int row = (rg << 4) + (wave << 2) + g;
  int kq = q << 2;
  const long base = ((long)b * T_) * C_ + (h << 6);
  const float* sR = rB + base;
  const float* sV = vvB + base;
  const float* sKr = krawB + base;
  int stok = tid >> 4;           // staging token within chunk (0..15)
  int spc = (tid & 15) << 2;     // channel offset within head (0..60)
  int lo = (stok << 6) + spc;
  int ch = (h << 6) + spc;
  // per-thread channel constants (loaded once)
  float4 td4 = *(const float4*)(tdec + ch);
  float4 ta4 = *(const float4*)(taa + ch);
  float4 tm4 = *(const float4*)(tma + ch);
  float4 tk4 = *(const float4*)(tmk + ch);
  float4 rbR, rbV, rbKr, rbWd, rbAd, rbMad, rbKd, rbMkd;
  auto loadc = [&](int c) {
    int m = (c << 4) + stok;
    long gr = (long)m * C_ + spc;
    rbR = *(const float4*)(sR + gr);
    rbV = *(const float4*)(sV + gr);
    rbKr = *(const float4*)(sKr + gr);
    long gd = (long)(b * T_ + m) * 5120 + ch;
    rbWd = *(const float4*)(d2B + gd);
    rbAd = *(const float4*)(d2B + gd + 1024);
    rbMad = *(const float4*)(d2B + gd + 2048);
    rbKd = *(const float4*)(d2B + gd + 3072);
    rbMkd = *(const float4*)(d2B + gd + 4096);
  };
  auto stage = [&](int buf, int cc) {
    // ---- fuse2 math (values loaded >=1 chunk ago, no stall) ----
    float kk0 = rbKr.x + rbKd.x, kk1 = rbKr.y + rbKd.y;
    float kk2 = rbKr.z + rbKd.z, kk3 = rbKr.w + rbKd.w;
    float ss = fmaf(kk0, kk0, fmaf(kk1, kk1, fmaf(kk2, kk2, kk3 * kk3)));
    ss = qsum16(ss);               // 16 lanes of this token = one DPP row
    float rn = 1.0f / fmaxf(sqrtf(ss), 1e-12f);
    float w0 = -softplusf_(-(td4.x + rbWd.x)) - 0.5f;
    float w1 = -softplusf_(-(td4.y + rbWd.y)) - 0.5f;
    float w2 = -softplusf_(-(td4.z + rbWd.z)) - 0.5f;
    float w3 = -softplusf_(-(td4.w + rbWd.w)) - 0.5f;
    float a0 = sigmoidf_(ta4.x + rbAd.x), a1 = sigmoidf_(ta4.y + rbAd.y);
    float a2 = sigmoidf_(ta4.z + rbAd.z), a3 = sigmoidf_(ta4.w + rbAd.w);
    float p0 = sigmoidf_(tm4.x + rbMad.x), p1 = sigmoidf_(tm4.y + rbMad.y);
    float p2 = sigmoidf_(tm4.z + rbMad.z), p3 = sigmoidf_(tm4.w + rbMad.w);
    float k0 = sigmoidf_(tk4.x + rbMkd.x), k1 = sigmoidf_(tk4.y + rbMkd.y);
    float k2 = sigmoidf_(tk4.z + rbMkd.z), k3 = sigmoidf_(tk4.w + rbMkd.w);
    float4 eww = {expf(w0), expf(w1), expf(w2), expf(w3)};
    float4 kfv;
    kfv.x = rbKr.x * (p0 + a0 * (1.f - p0)) * expf(w0 * k0);
    kfv.y = rbKr.y * (p1 + a1 * (1.f - p1)) * expf(w1 * k1);
    kfv.z = rbKr.z * (p2 + a2 * (1.f - p2)) * expf(w2 * k2);
    kfv.w = rbKr.w * (p3 + a3 * (1.f - p3)) * expf(w3 * k3);
    float4 kknv = {kk0 * rn, kk1 * rn, kk2 * rn, kk3 * rn};
    float4 bbv = {-kknv.x * a0, -kknv.y * a1, -kknv.z * a2, -kknv.w * a3};
    *(float4*)&lds[buf][0][lo] = kknv;
    *(float4*)&lds[buf][1][lo] = eww;
    *(float4*)&lds[buf][2][lo] = kfv;
    *(float4*)&lds[buf][3][lo] = bbv;
    *(float4*)&lds[buf][4][lo] = rbR;
    *(float4*)&lds[buf][5][lo] = rbV;
    *(float4*)(kfB + base + (long)((cc << 4) + stok) * C_ + spc) = kfv;
  };
  float S0 = 0.f, S1 = 0.f, S2 = 0.f, S3 = 0.f;
  float ypv = 0.f;
  float4 Q0kk, Q0ew, Q0k, Q0bb, Q0r; float Q0v;
  float4 Q1kk, Q1ew, Q1k, Q1bb, Q1r; float Q1v;
  float4 Q2kk, Q2ew, Q2k, Q2bb, Q2r; float Q2v;

#define PF(i, tt) { int tb_ = ((tt) << 6); \
    Q##i##kk = *(const float4*)&lds[cur][0][tb_ + kq]; \
    Q##i##ew = *(const float4*)&lds[cur][1][tb_ + kq]; \
    Q##i##k  = *(const float4*)&lds[cur][2][tb_ + kq]; \
    Q##i##bb = *(const float4*)&lds[cur][3][tb_ + kq]; \
    Q##i##r  = *(const float4*)&lds[cur][4][tb_ + kq]; \
    Q##i##v  = lds[cur][5][tb_ + row]; }
#define SBAR __builtin_amdgcn_sched_barrier(0x7)
#define ST(i, gtok, FIRSTT) { \
    float p_ = fmaf(S1, Q##i##kk.y, S0 * Q##i##kk.x) + \
               fmaf(S3, Q##i##kk.w, S2 * Q##i##kk.z); \
    float yo_ = ypv; \
    qsum16x2(p_, yo_); \
    if (q == 0 && !((FIRSTT) && c == 0)) \
      yB[base + (long)((gtok) - 1) * C_ + row] = yo_; \
    float n0 = fmaf(S0, Q##i##ew.x, Q##i##v * Q##i##k.x); \
    float n1 = fmaf(S1, Q##i##ew.y, Q##i##v * Q##i##k.y); \
    float n2 = fmaf(S2, Q##i##ew.z, Q##i##v * Q##i##k.z); \
    float n3 = fmaf(S3, Q##i##ew.w, Q##i##v * Q##i##k.w); \
    S0 = fmaf(p_, Q##i##bb.x, n0); \
    S1 = fmaf(p_, Q##i##bb.y, n1); \
    S2 = fmaf(p_, Q##i##bb.z, n2); \
    S3 = fmaf(p_, Q##i##bb.w, n3); \
    ypv = fmaf(S1, Q##i##r.y, S0 * Q##i##r.x) + \
          fmaf(S3, Q##i##r.w, S2 * Q##i##r.z); }

  loadc(0);
  stage(0, 0);
  loadc(1);
  __syncthreads();
  int cur = 0;
  for (int c = 0; c < NCHUNK; c++) {
    int t0 = c << 4;
    PF(0, 0); PF(1, 1);
    if (c + 1 < NCHUNK) stage(cur ^ 1, c + 1);
    if (c + 2 < NCHUNK) loadc(c + 2);
    SBAR;
    PF(2, 2);  SBAR; ST(0, t0 + 0, true);
    PF(0, 3);  SBAR; ST(1, t0 + 1, false);
    PF(1, 4);  SBAR; ST(2, t0 + 2, false);
    PF(2, 5);  SBAR; ST(0, t0 + 3, false);
    PF(0, 6);  SBAR; ST(1, t0 + 4, false);
    PF(1, 7);  SBAR; ST(2, t0 + 5, false);
    PF(2, 8);  SBAR; ST(0, t0 + 6, false);
    PF(0, 9);  SBAR; ST(1, t0 + 7, false);
    PF(1, 10); SBAR; ST(2, t0 + 8, false);
    PF(2, 11); SBAR; ST(0, t0 + 9, false);
    PF(0, 12); SBAR; ST(1, t0 + 10, false);
    PF(1, 13); SBAR; ST(2, t0 + 11, false);
    PF(2, 14); SBAR; ST(0, t0 + 12, false);
    PF(0, 15); SBAR; ST(1, t0 + 13, false);
    ST(2, t0 + 14, false);
    ST(0, t0 + 15, false);
    __syncthreads();
    cur ^= 1;
  }
  {
    float yo = qsum16(ypv);
    if (q == 0) yB[base + (long)(T_ - 1) * C_ + row] = yo;
  }
#undef PF
#undef SBAR
#undef ST
}

// ---------------- K7: GroupNorm + bonus + gate (bf16 out) -------------------
__global__ __launch_bounds__(256) void gnout_kernel(
    const float* __restrict__ y, const float* __restrict__ r,
    const float* __restrict__ kf, const float* __restrict__ v,
    const float* __restrict__ g,
    const float* __restrict__ lnw, const float* __restrict__ lnb,
    const float* __restrict__ fa, bf16* __restrict__ z) {
  int tid = threadIdx.x;
  int w = tid >> 6, lane = tid & 63;
  int gi = (blockIdx.x << 2) + w;
  int h = gi & 15, mt = gi >> 4;
  long off = (long)mt * C_ + (h << 6) + lane;
  float yv = y[off];
  float s = yv;
  s += __shfl_xor(s, 1); s += __shfl_xor(s, 2); s += __shfl_xor(s, 4);
  s += __shfl_xor(s, 8); s += __shfl_xor(s, 16); s += __shfl_xor(s, 32);
  float mu = s * (1.0f / 64.0f);
  float d = yv - mu;
  float s2 = d * d;
  s2 += __shfl_xor(s2, 1); s2 += __shfl_xor(s2, 2); s2 += __shfl_xor(s2, 4);
  s2 += __shfl_xor(s2, 8); s2 += __shfl_xor(s2, 16); s2 += __shfl_xor(s2, 32);
  float var = s2 * (1.0f / 64.0f);
  int hc = (h << 6) + lane;
  float dot = r[off] * kf[off] * fa[hc];
  dot += __shfl_xor(dot, 1); dot += __shfl_xor(dot, 2); dot += __shfl_xor(dot, 4);
  dot += __shfl_xor(dot, 8); dot += __shfl_xor(dot, 16); dot += __shfl_xor(dot, 32);
  float yn = d * rsqrtf(var + 0.00064f) * lnw[hc] + lnb[hc];
  z[off] = f2bf((yn + dot * v[off]) * g[off]);
}

extern "C" void kernel_launch(void* const* d_in, const int* in_sizes, int n_in,
                              void* d_out, int out_size, void* d_ws, size_t ws_size,
                              hipStream_t stream) {
  const float* x = (const float*)d_in[0];
  const float* tmx = (const float*)d_in[1];
  const float* tmaa = (const float*)d_in[2];
  const float* tmw1 = (const float*)d_in[3];
  const float* tmw2 = (const float*)d_in[4];
  const float* tdec = (const float*)d_in[5];
  const float* tdw1 = (const float*)d_in[6];
  const float* tdw2 = (const float*)d_in[7];
  const float* taa5 = (const float*)d_in[8];
  const float* taw1 = (const float*)d_in[9];
  const float* taw2 = (const float*)d_in[10];
  const float* tkw1 = (const float*)d_in[11];
  const float* tkw2 = (const float*)d_in[12];
  const float* gw1 = (const float*)d_in[13];
  const float* gw2 = (const float*)d_in[14];
  const float* tmia = (const float*)d_in[15];
  const float* maw1 = (const float*)d_in[16];
  const float* maw2 = (const float*)d_in[17];
  const float* tmik = (const float*)d_in[18];
  const float* mkw1 = (const float*)d_in[19];
  const float* mkw2 = (const float*)d_in[20];
  const float* wrec = (const float*)d_in[21];
  const float* wkey = (const float*)d_in[22];
  const float* wval = (const float*)d_in[23];
  const float* wout = (const float*)d_in[24];
  const float* lnw = (const float*)d_in[25];
  const float* lnb = (const float*)d_in[26];
  const float* faaa = (const float*)d_in[27];

  const long MT = 2048, CC = 1024;
  char* base = (char*)d_ws;
  float* y = (float*)base;     base += MT * CC * 4;
  bf16* xrgb = (bf16*)base;    base += MT * CC * 2;   // ┐ kfin overlays (8MB)
  bf16* xwab = (bf16*)base;    base += MT * CC * 2;   // ┘
  bf16* xkb = (bf16*)base;     base += MT * CC * 2;
  bf16* xvb = (bf16*)base;     base += MT * CC * 2;
  float* rr = (float*)base;    base += MT * CC * 4;
  float* kraw = (float*)base;  base += MT * CC * 4;
  float* vv = (float*)base;    base += MT * CC * 4;
  float* gg = (float*)base;    base += MT * CC * 4;
  bf16* g1b = (bf16*)base;     base += MT * 128 * 2;
  bf16* out12b = (bf16*)base;  base += MT * 128 * 2;  // [w1|a1|ma1|kk1|mk1]
  bf16* zb = (bf16*)base;      base += MT * CC * 2;
  bf16* mixb = (bf16*)base;    base += MT * 128 * 2;
  float* d2 = (float*)base;    base += MT * 5120L * 4; // fuse2 dots (fp32)
  bf16* tmw1b = (bf16*)base;   base += 128 * CC * 2;
  bf16* wrecb = (bf16*)base;   base += CC * CC * 2;
  bf16* gw1b = (bf16*)base;    base += 128 * CC * 2;
  bf16* gw2b = (bf16*)base;    base += CC * 128 * 2;
  bf16* wkeyb = (bf16*)base;   base += CC * CC * 2;
  bf16* wvalb = (bf16*)base;   base += CC * CC * 2;
  bf16* woutb = (bf16*)base;   base += CC * CC * 2;
  bf16* wskb = (bf16*)base;    base += 32 * CC * 2;
  bf16* wswab = (bf16*)base;   base += 96 * CC * 2;
  bf16* tmw2e = (bf16*)base;   base += 4096L * 128 * 2;
  bf16* w2e5b = (bf16*)base;   base += 5120L * 128 * 2;
  // aliases (dead-buffer reuse, verified non-overlapping in time):
  float* kfin = (float*)xrgb;  // xrg/xwa bf16 dead after batch6; scan writes kfin

  // one launch: all conversions/expansions + the mix GEMM (raw-f32 W staging)
  cvt_mix_kernel<<<5792, 256, 0, stream>>>(
      tmw1, wrec, gw1, gw2, wkey, wval, wout,
      tmw1b, wrecb, gw1b, gw2b, wkeyb, wvalb, woutb,
      tkw1, mkw1, tdw1, taw1, maw1, wskb, wswab,
      tmw2, tdw2, tkw2, taw2, maw2, mkw2,
      tmw2e, w2e5b, x, tmx, mixb);

  // deltas GEMM with fused mix-apply epilogue -> xrg/xwa/xk/xv
  gemm_mixapply_kernel<<<dim3(64, 16), 256, 0, stream>>>(
      mixb, tmw2e, x, tmaa, xrgb, xwab, xkb, xvb);
  // 6 independent K=1024 GEMMs, one launch; z=3/z=5 write slices of out12b
  {
    GemmBatch gb = {};
    gb.A[0] = xrgb; gb.W[0] = wrecb; gb.Cf[0] = rr;      gb.Cb[0] = nullptr; gb.N[0] = 1024; gb.actN[0] = 0;   gb.ldc[0] = 1024; gb.coff[0] = 0;
    gb.A[1] = xrgb; gb.W[1] = gw1b;  gb.Cf[1] = nullptr; gb.Cb[1] = g1b;     gb.N[1] = 128;  gb.actN[1] = 128; gb.ldc[1] = 128;  gb.coff[1] = 0;
    gb.A[2] = xkb;  gb.W[2] = wkeyb; gb.Cf[2] = kraw;    gb.Cb[2] = nullptr; gb.N[2] = 1024; gb.actN[2] = 0;   gb.ldc[2] = 1024; gb.coff[2] = 0;
    gb.A[3] = xkb;  gb.W[3] = wskb;  gb.Cf[3] = nullptr; gb.Cb[3] = out12b;  gb.N[3] = 32;   gb.actN[3] = 16;  gb.ldc[3] = 128;  gb.coff[3] = 96;
    gb.A[4] = xvb;  gb.W[4] = wvalb; gb.Cf[4] = vv;      gb.Cb[4] = nullptr; gb.N[4] = 1024; gb.actN[4] = 0;   gb.ldc[4] = 1024; gb.coff[4] = 0;
    gb.A[5] = xwab; gb.W[5] = wswab; gb.Cf[5] = nullptr; gb.Cb[5] = out12b;  gb.N[5] = 96;   gb.actN[5] = 64;  gb.ldc[5] = 128;  gb.coff[5] = 0;
    gemm_batch_kernel<<<dim3(16, 16, 6), 256, 0, stream>>>(gb, 1024);
  }
  // batch2 (K=128): gg GEMM + fuse2-dots GEMM (d2 = out12b x w2e5^T, fp32)
  {
    GemmBatch gb = {};
    gb.A[0] = g1b;    gb.W[0] = gw2b;  gb.Cf[0] = gg; gb.Cb[0] = nullptr; gb.N[0] = 1024; gb.actN[0] = 0; gb.ldc[0] = 1024; gb.coff[0] = 0;
    gb.A[1] = out12b; gb.W[1] = w2e5b; gb.Cf[1] = d2; gb.Cb[1] = nullptr; gb.N[1] = 5120; gb.actN[1] = 0; gb.ldc[1] = 5120; gb.coff[1] = 0;
    gemm_batch_kernel<<<dim3(80, 16, 2), 256, 0, stream>>>(gb, 128);
  }
  // scan with fused fuse2 (reads kraw + d2 slices; writes y + kfin)
  scan_kernel<<<128, 256, 0, stream>>>(rr, vv, kraw, d2,
                                       tdec, taa5, tmia, tmik, y, kfin);
  gnout_kernel<<<8192, 256, 0, stream>>>(y, rr, kfin, vv, gg, lnw, lnb, faaa, zb);
  // output GEMM: (2048x1024)x(1024x1024)^T
  {
    GemmBatch gb = {};
    gb.A[0] = zb; gb.W[0] = woutb; gb.Cf[0] = (float*)d_out; gb.Cb[0] = nullptr;
    gb.N[0] = 1024; gb.actN[0] = 0; gb.ldc[0] = 1024; gb.coff[0] = 0;
    gemm_batch_kernel<<<dim3(16, 16, 1), 256, 0, stream>>>(gb, 1024);
  }
}

// Round 12
// 426.837 us; speedup vs baseline: 1.3513x; 1.3513x over previous
//
#include <hip/hip_runtime.h>
#include <hip/hip_bf16.h>

typedef __hip_bfloat16 bf16;

#define B_ 2
#define T_ 1024
#define C_ 1024
#define H_ 16
#define N_ 64

using short4v = __attribute__((ext_vector_type(4))) short;
using short8 = __attribute__((ext_vector_type(8))) short;
using f32x4 = __attribute__((ext_vector_type(4))) float;

__device__ __forceinline__ float bs2f(short s) {
  return __uint_as_float(((unsigned int)(unsigned short)s) << 16);
}
__device__ __forceinline__ bf16 f2bf(float f) { return __float2bfloat16(f); }
__device__ __forceinline__ short bfbits(float f) {
  bf16 h = __float2bfloat16(f);
  return *reinterpret_cast<short*>(&h);
}
__device__ __forceinline__ float sigmoidf_(float x) { return 1.0f / (1.0f + expf(-x)); }
__device__ __forceinline__ float softplusf_(float x) {
  return fmaxf(x, 0.0f) + log1pf(expf(-fabsf(x)));
}
// Full 16-lane-row sum, all lanes receive the result. Pure-VALU DPP.
__device__ __forceinline__ float qsum16(float x) {
  int a = __builtin_amdgcn_update_dpp(0, __float_as_int(x), 0xB1, 0xF, 0xF, true);
  x += __int_as_float(a);
  int b = __builtin_amdgcn_update_dpp(0, __float_as_int(x), 0x4E, 0xF, 0xF, true);
  x += __int_as_float(b);
  int c = __builtin_amdgcn_update_dpp(0, __float_as_int(x), 0x124, 0xF, 0xF, true);
  x += __int_as_float(c);
  int d = __builtin_amdgcn_update_dpp(0, __float_as_int(x), 0x128, 0xF, 0xF, true);
  x += __int_as_float(d);
  return x;
}
// Two interleaved 16-lane-row sums (overlaps token t's sab chain with token
// t-1's y chain; see scan_kernel comment).
__device__ __forceinline__ void qsum16x2(float& x, float& y) {
  int a0 = __builtin_amdgcn_update_dpp(0, __float_as_int(x), 0xB1, 0xF, 0xF, true);
  int b0 = __builtin_amdgcn_update_dpp(0, __float_as_int(y), 0xB1, 0xF, 0xF, true);
  x += __int_as_float(a0); y += __int_as_float(b0);
  int a1 = __builtin_amdgcn_update_dpp(0, __float_as_int(x), 0x4E, 0xF, 0xF, true);
  int b1 = __builtin_amdgcn_update_dpp(0, __float_as_int(y), 0x4E, 0xF, 0xF, true);
  x += __int_as_float(a1); y += __int_as_float(b1);
  int a2 = __builtin_amdgcn_update_dpp(0, __float_as_int(x), 0x124, 0xF, 0xF, true);
  int b2 = __builtin_amdgcn_update_dpp(0, __float_as_int(y), 0x124, 0xF, 0xF, true);
  x += __int_as_float(a2); y += __int_as_float(b2);
  int a3 = __builtin_amdgcn_update_dpp(0, __float_as_int(x), 0x128, 0xF, 0xF, true);
  int b3 = __builtin_amdgcn_update_dpp(0, __float_as_int(y), 0x128, 0xF, 0xF, true);
  x += __int_as_float(a3); y += __int_as_float(b3);
}

// ---------------- K0: cvt + expansions + mix-GEMM, ONE launch ---------------
// Blocks 0..5759: weight fp32->bf16 conversions + tmw2e/w2e5 expansions.
// Blocks 5760..5791: the mix GEMM (A = token-shifted x on the fly; W staged
// directly from f32 tmw1 -> no dependency on the cvt blocks). R11 measured
// this merge at ~-24us vs separate cvt+mix launches; kept.
__global__ __launch_bounds__(256) void cvt_mix_kernel(
    const float* __restrict__ s0, const float* __restrict__ s1,
    const float* __restrict__ s2, const float* __restrict__ s3,
    const float* __restrict__ s4, const float* __restrict__ s5,
    const float* __restrict__ s6,
    bf16* __restrict__ d0, bf16* __restrict__ d1, bf16* __restrict__ d2w,
    bf16* __restrict__ d3, bf16* __restrict__ d4, bf16* __restrict__ d5,
    bf16* __restrict__ d6,
    const float* __restrict__ tkw1, const float* __restrict__ mkw1,
    const float* __restrict__ tdw1, const float* __restrict__ taw1,
    const float* __restrict__ maw1,
    bf16* __restrict__ wsk, bf16* __restrict__ wswa,
    const float* __restrict__ tmw2, const float* __restrict__ tdw2,
    const float* __restrict__ tkw2, const float* __restrict__ taw2,
    const float* __restrict__ maw2, const float* __restrict__ mkw2,
    bf16* __restrict__ tmw2e, bf16* __restrict__ w2e5,
    const float* __restrict__ x, const float* __restrict__ tmx,
    bf16* __restrict__ mixb) {
  long bidx = blockIdx.x;
  if (bidx >= 5760) {                     // -------- mix GEMM blocks --------
    __shared__ __align__(16) bf16 As[128][72];
    __shared__ __align__(16) bf16 Ws[64][72];
    const int K = 1024;
    int mb = (int)(bidx - 5760);
    int n0 = (mb & 1) << 6;
    int m0 = (mb >> 1) << 7;
    int tid = threadIdx.x;
    int arow = tid >> 1, acol = (tid & 1) << 5;
    int wrow = tid >> 2, wcol = (tid & 3) << 4;
    int wv = tid >> 6, lane = tid & 63;
    int fr = lane & 15, fq = lane >> 4;
    int grow = m0 + arow;
    int t = grow & (T_ - 1);
    const float* xp = x + (long)grow * C_ + acol;
    const float* Wp = s0 + (long)(n0 + wrow) * K + wcol;  // raw f32 tmw1
    f32x4 a00 = {0.f, 0.f, 0.f, 0.f};
    f32x4 a01 = a00, a02 = a00, a03 = a00, a10 = a00, a11 = a00, a12 = a00, a13 = a00;
    for (int k0 = 0; k0 < K; k0 += 64) {
#pragma unroll
      for (int jj = 0; jj < 4; jj++) {
        int co = k0 + (jj << 3);
        float4 c0 = *(const float4*)(xp + co);
        float4 c1 = *(const float4*)(xp + co + 4);
        float4 q0 = {0.f, 0.f, 0.f, 0.f}, q1 = q0;
        if (t > 0) {
          q0 = *(const float4*)(xp + co - C_);
          q1 = *(const float4*)(xp + co + 4 - C_);
        }
        float4 m0v = *(const float4*)(tmx + co + acol);
        float4 m1v = *(const float4*)(tmx + co + acol + 4);
        short8 sv;
        sv[0] = bfbits(fmaf(q0.x - c0.x, m0v.x, c0.x));
        sv[1] = bfbits(fmaf(q0.y - c0.y, m0v.y, c0.y));
        sv[2] = bfbits(fmaf(q0.z - c0.z, m0v.z, c0.z));
        sv[3] = bfbits(fmaf(q0.w - c0.w, m0v.w, c0.w));
        sv[4] = bfbits(fmaf(q1.x - c1.x, m1v.x, c1.x));
        sv[5] = bfbits(fmaf(q1.y - c1.y, m1v.y, c1.y));
        sv[6] = bfbits(fmaf(q1.z - c1.z, m1v.z, c1.z));
        sv[7] = bfbits(fmaf(q1.w - c1.w, m1v.w, c1.w));
        *(short8*)&As[arow][acol + (jj << 3)] = sv;
      }
      {
        float4 w0 = *(const float4*)(Wp + k0);
        float4 w1 = *(const float4*)(Wp + k0 + 4);
        float4 w2 = *(const float4*)(Wp + k0 + 8);
        float4 w3 = *(const float4*)(Wp + k0 + 12);
        short8 wv0, wv1;
        wv0[0] = bfbits(w0.x); wv0[1] = bfbits(w0.y); wv0[2] = bfbits(w0.z); wv0[3] = bfbits(w0.w);
        wv0[4] = bfbits(w1.x); wv0[5] = bfbits(w1.y); wv0[6] = bfbits(w1.z); wv0[7] = bfbits(w1.w);
        wv1[0] = bfbits(w2.x); wv1[1] = bfbits(w2.y); wv1[2] = bfbits(w2.z); wv1[3] = bfbits(w2.w);
        wv1[4] = bfbits(w3.x); wv1[5] = bfbits(w3.y); wv1[6] = bfbits(w3.z); wv1[7] = bfbits(w3.w);
        *(short8*)&Ws[wrow][wcol] = wv0;
        *(short8*)&Ws[wrow][wcol + 8] = wv1;
      }
      __syncthreads();
#pragma unroll
      for (int kk = 0; kk < 2; kk++) {
        int ko = (fq << 3) + (kk << 5);
        short8 af0 = *(const short8*)&As[(wv << 5) + fr][ko];
        short8 af1 = *(const short8*)&As[(wv << 5) + 16 + fr][ko];
        short8 b0 = *(const short8*)&Ws[fr][ko];
        short8 b1 = *(const short8*)&Ws[16 + fr][ko];
        short8 b2 = *(const short8*)&Ws[32 + fr][ko];
        short8 b3 = *(const short8*)&Ws[48 + fr][ko];
        a00 = __builtin_amdgcn_mfma_f32_16x16x32_bf16(af0, b0, a00, 0, 0, 0);
        a01 = __builtin_amdgcn_mfma_f32_16x16x32_bf16(af0, b1, a01, 0, 0, 0);
        a02 = __builtin_amdgcn_mfma_f32_16x16x32_bf16(af0, b2, a02, 0, 0, 0);
        a03 = __builtin_amdgcn_mfma_f32_16x16x32_bf16(af0, b3, a03, 0, 0, 0);
        a10 = __builtin_amdgcn_mfma_f32_16x16x32_bf16(af1, b0, a10, 0, 0, 0);
        a11 = __builtin_amdgcn_mfma_f32_16x16x32_bf16(af1, b1, a11, 0, 0, 0);
        a12 = __builtin_amdgcn_mfma_f32_16x16x32_bf16(af1, b2, a12, 0, 0, 0);
        a13 = __builtin_amdgcn_mfma_f32_16x16x32_bf16(af1, b3, a13, 0, 0, 0);
      }
      __syncthreads();
    }
    const int Nz = 128;
    int ocol = n0 + fr;
    int orow0 = m0 + (wv << 5) + (fq << 2);
#define WRM(accv, mf, nt) { int col = ocol + ((nt) << 4); \
    _Pragma("unroll") for (int r = 0; r < 4; r++) { \
      long oi = (long)(orow0 + ((mf) << 4) + r) * Nz + col; \
      mixb[oi] = f2bf(tanhf(accv[r])); } }
    WRM(a00, 0, 0) WRM(a01, 0, 1) WRM(a02, 0, 2) WRM(a03, 0, 3)
    WRM(a10, 1, 0) WRM(a11, 1, 1) WRM(a12, 1, 2) WRM(a13, 1, 3)
#undef WRM
    return;
  }
  const float* s; bf16* d; long off;
  if (bidx < 4480) {                      // big weights
    long i4 = bidx * 256 + threadIdx.x;
    if (i4 < 32768) { s = s0; d = d0; off = i4; }
    else if (i4 < 294912) { s = s1; d = d1; off = i4 - 32768; }
    else if (i4 < 327680) { s = s2; d = d2w; off = i4 - 294912; }
    else if (i4 < 360448) { s = s3; d = d3; off = i4 - 327680; }
    else if (i4 < 622592) { s = s4; d = d4; off = i4 - 360448; }
    else if (i4 < 884736) { s = s5; d = d5; off = i4 - 622592; }
    else { s = s6; d = d6; off = i4 - 884736; }
  } else if (bidx < 4608) {               // LoRA-1 packs
    long i4 = (bidx - 4480) * 256 + threadIdx.x;  // < 32768
    long so, dof;
    if (i4 < 4096) { s = tkw1; so = i4; d = wsk; dof = i4; }
    else if (i4 < 8192) { s = mkw1; so = i4 - 4096; d = wsk; dof = i4; }
    else if (i4 < 24576) { s = tdw1; so = i4 - 8192; d = wswa; dof = i4 - 8192; }
    else if (i4 < 28672) { s = taw1; so = i4 - 24576; d = wswa; dof = i4 - 8192; }
    else { s = maw1; so = i4 - 28672; d = wswa; dof = i4 - 8192; }
    float4 v = *(const float4*)(s + so * 4);
    d[dof * 4 + 0] = f2bf(v.x); d[dof * 4 + 1] = f2bf(v.y);
    d[dof * 4 + 2] = f2bf(v.z); d[dof * 4 + 3] = f2bf(v.w);
    return;
  } else if (bidx < 5120) {               // tmw2e expansion (4096x128)
    long i4 = (bidx - 4608) * 256 + threadIdx.x;  // < 131072
    long n = i4 >> 5;
    int k0 = (int)(i4 & 31) << 2;
    int f = (int)(n >> 10);
    float4 v = {0.f, 0.f, 0.f, 0.f};
    if ((k0 >> 5) == f) v = *(const float4*)(tmw2 + n * 32 + (k0 & 31));
    tmw2e[i4 * 4 + 0] = f2bf(v.x);
    tmw2e[i4 * 4 + 1] = f2bf(v.y);
    tmw2e[i4 * 4 + 2] = f2bf(v.z);
    tmw2e[i4 * 4 + 3] = f2bf(v.w);
    return;
  } else {                                // w2e5 expansion (5120x128)
    long i4 = (bidx - 5120) * 256 + threadIdx.x;  // < 163840
    long rowi = i4 >> 5;                  // 0..5119
    int k0 = (int)(i4 & 31) << 2;         // 0..124
    int j = (int)(rowi >> 10);
    int c = (int)(rowi & 1023);
    float4 v = {0.f, 0.f, 0.f, 0.f};
    if (j == 0) { if (k0 < 64) v = *(const float4*)(tdw2 + c * 64 + k0); }
    else if (j == 1) { if (k0 >= 64 && k0 < 80) v = *(const float4*)(taw2 + c * 16 + (k0 - 64)); }
    else if (j == 2) { if (k0 >= 80 && k0 < 96) v = *(const float4*)(maw2 + c * 16 + (k0 - 80)); }
    else if (j == 3) { if (k0 >= 96 && k0 < 112) v = *(const float4*)(tkw2 + c * 16 + (k0 - 96)); }
    else { if (k0 >= 112) v = *(const float4*)(mkw2 + c * 16 + (k0 - 112)); }
    w2e5[i4 * 4 + 0] = f2bf(v.x);
    w2e5[i4 * 4 + 1] = f2bf(v.y);
    w2e5[i4 * 4 + 2] = f2bf(v.z);
    w2e5[i4 * 4 + 3] = f2bf(v.w);
    return;
  }
  float4 v = *(const float4*)(s + off * 4);
  d[off * 4 + 0] = f2bf(v.x);
  d[off * 4 + 1] = f2bf(v.y);
  d[off * 4 + 2] = f2bf(v.z);
  d[off * 4 + 3] = f2bf(v.w);
}

// ---------------- Batched MFMA GEMM: C[z] = A[z] * W[z]^T -------------------
// 128x64 tile, 4 waves x (2 M-frags x 4 N-frags). ldc/coff let several GEMMs
// write column slices of one combined buffer (out12).
struct GemmBatch {
  const bf16* A[6]; const bf16* W[6];
  float* Cf[6]; bf16* Cb[6];
  int N[6]; int actN[6]; int ldc[6]; int coff[6];
};

__global__ __launch_bounds__(256) void gemm_batch_kernel(GemmBatch gb, int K) {
  __shared__ __align__(16) bf16 As[128][72];
  __shared__ __align__(16) bf16 Ws[64][72];
  int z = blockIdx.z;
  int Nz = gb.N[z];
  int n0 = blockIdx.x << 6;
  if (n0 >= Nz) return;
  int m0 = blockIdx.y << 7;
  int actN = gb.actN[z];
  int ldc = gb.ldc[z], coff = gb.coff[z];
  const bf16* A = gb.A[z];
  const bf16* W = gb.W[z];
  float* Cf = gb.Cf[z];
  bf16* Cb = gb.Cb[z];
  int tid = threadIdx.x;
  int arow = tid >> 1, acol = (tid & 1) << 5;
  int wrow = tid >> 2, wcol = (tid & 3) << 4;
  int wv = tid >> 6, lane = tid & 63;
  int fr = lane & 15, fq = lane >> 4;
  bool wok = (n0 + wrow) < Nz;
  const bf16* Ap = A + (long)(m0 + arow) * K + acol;
  const bf16* Wp = W + (long)(n0 + wrow) * K + wcol;
  short8 zz = {0, 0, 0, 0, 0, 0, 0, 0};
  f32x4 a00 = {0.f, 0.f, 0.f, 0.f};
  f32x4 a01 = a00, a02 = a00, a03 = a00, a10 = a00, a11 = a00, a12 = a00, a13 = a00;
  for (int k0 = 0; k0 < K; k0 += 64) {
    *(short8*)&As[arow][acol] = *(const short8*)(Ap + k0);
    *(short8*)&As[arow][acol + 8] = *(const short8*)(Ap + k0 + 8);
    *(short8*)&As[arow][acol + 16] = *(const short8*)(Ap + k0 + 16);
    *(short8*)&As[arow][acol + 24] = *(const short8*)(Ap + k0 + 24);
    *(short8*)&Ws[wrow][wcol] = wok ? *(const short8*)(Wp + k0) : zz;
    *(short8*)&Ws[wrow][wcol + 8] = wok ? *(const short8*)(Wp + k0 + 8) : zz;
    __syncthreads();
#pragma unroll
    for (int kk = 0; kk < 2; kk++) {
      int ko = (fq << 3) + (kk << 5);
      short8 af0 = *(const short8*)&As[(wv << 5) + fr][ko];
      short8 af1 = *(const short8*)&As[(wv << 5) + 16 + fr][ko];
      short8 b0 = *(const short8*)&Ws[fr][ko];
      short8 b1 = *(const short8*)&Ws[16 + fr][ko];
      short8 b2 = *(const short8*)&Ws[32 + fr][ko];
      short8 b3 = *(const short8*)&Ws[48 + fr][ko];
      a00 = __builtin_amdgcn_mfma_f32_16x16x32_bf16(af0, b0, a00, 0, 0, 0);
      a01 = __builtin_amdgcn_mfma_f32_16x16x32_bf16(af0, b1, a01, 0, 0, 0);
      a02 = __builtin_amdgcn_mfma_f32_16x16x32_bf16(af0, b2, a02, 0, 0, 0);
      a03 = __builtin_amdgcn_mfma_f32_16x16x32_bf16(af0, b3, a03, 0, 0, 0);
      a10 = __builtin_amdgcn_mfma_f32_16x16x32_bf16(af1, b0, a10, 0, 0, 0);
      a11 = __builtin_amdgcn_mfma_f32_16x16x32_bf16(af1, b1, a11, 0, 0, 0);
      a12 = __builtin_amdgcn_mfma_f32_16x16x32_bf16(af1, b2, a12, 0, 0, 0);
      a13 = __builtin_amdgcn_mfma_f32_16x16x32_bf16(af1, b3, a13, 0, 0, 0);
    }
    __syncthreads();
  }
  int ocol = n0 + fr;
  int orow0 = m0 + (wv << 5) + (fq << 2);
#define WRB(accv, mf, nt) { int col = ocol + ((nt) << 4); if (col < Nz) { \
    _Pragma("unroll") for (int r = 0; r < 4; r++) { \
      float vvv = accv[r]; if (col < actN) vvv = tanhf(vvv); \
      long oi = (long)(orow0 + ((mf) << 4) + r) * ldc + coff + col; \
      if (Cb) Cb[oi] = f2bf(vvv); else Cf[oi] = vvv; } } }
  WRB(a00, 0, 0) WRB(a01, 0, 1) WRB(a02, 0, 2) WRB(a03, 0, 3)
  WRB(a10, 1, 0) WRB(a11, 1, 1) WRB(a12, 1, 2) WRB(a13, 1, 3)
#undef WRB
}

// ---------------- deltas GEMM with fused mix-apply epilogue -----------------
__global__ __launch_bounds__(256) void gemm_mixapply_kernel(
    const bf16* __restrict__ A, const bf16* __restrict__ W,
    const float* __restrict__ x, const float* __restrict__ tmaa,
    bf16* __restrict__ xrg, bf16* __restrict__ xwa,
    bf16* __restrict__ xk, bf16* __restrict__ xv) {
  __shared__ __align__(16) bf16 As[128][72];
  __shared__ __align__(16) bf16 Ws[64][72];
  const int K = 128;
  int n0 = blockIdx.x << 6;   // 0..4032
  int m0 = blockIdx.y << 7;
  int tid = threadIdx.x;
  int arow = tid >> 1, acol = (tid & 1) << 5;
  int wrow = tid >> 2, wcol = (tid & 3) << 4;
  int wv = tid >> 6, lane = tid & 63;
  int fr = lane & 15, fq = lane >> 4;
  const bf16* Ap = A + (long)(m0 + arow) * K + acol;
  const bf16* Wp = W + (long)(n0 + wrow) * K + wcol;
  f32x4 a00 = {0.f, 0.f, 0.f, 0.f};
  f32x4 a01 = a00, a02 = a00, a03 = a00, a10 = a00, a11 = a00, a12 = a00, a13 = a00;
  for (int k0 = 0; k0 < K; k0 += 64) {
    *(short8*)&As[arow][acol] = *(const short8*)(Ap + k0);
    *(short8*)&As[arow][acol + 8] = *(const short8*)(Ap + k0 + 8);
    *(short8*)&As[arow][acol + 16] = *(const short8*)(Ap + k0 + 16);
    *(short8*)&As[arow][acol + 24] = *(const short8*)(Ap + k0 + 24);
    *(short8*)&Ws[wrow][wcol] = *(const short8*)(Wp + k0);
    *(short8*)&Ws[wrow][wcol + 8] = *(const short8*)(Wp + k0 + 8);
    __syncthreads();
#pragma unroll
    for (int kk = 0; kk < 2; kk++) {
      int ko = (fq << 3) + (kk << 5);
      short8 af0 = *(const short8*)&As[(wv << 5) + fr][ko];
      short8 af1 = *(const short8*)&As[(wv << 5) + 16 + fr][ko];
      short8 b0 = *(const short8*)&Ws[fr][ko];
      short8 b1 = *(const short8*)&Ws[16 + fr][ko];
      short8 b2 = *(const short8*)&Ws[32 + fr][ko];
      short8 b3 = *(const short8*)&Ws[48 + fr][ko];
      a00 = __builtin_amdgcn_mfma_f32_16x16x32_bf16(af0, b0, a00, 0, 0, 0);
      a01 = __builtin_amdgcn_mfma_f32_16x16x32_bf16(af0, b1, a01, 0, 0, 0);
      a02 = __builtin_amdgcn_mfma_f32_16x16x32_bf16(af0, b2, a02, 0, 0, 0);
      a03 = __builtin_amdgcn_mfma_f32_16x16x32_bf16(af0, b3, a03, 0, 0, 0);
      a10 = __builtin_amdgcn_mfma_f32_16x16x32_bf16(af1, b0, a10, 0, 0, 0);
      a11 = __builtin_amdgcn_mfma_f32_16x16x32_bf16(af1, b1, a11, 0, 0, 0);
      a12 = __builtin_amdgcn_mfma_f32_16x16x32_bf16(af1, b2, a12, 0, 0, 0);
      a13 = __builtin_amdgcn_mfma_f32_16x16x32_bf16(af1, b3, a13, 0, 0, 0);
    }
    __syncthreads();
  }
  int f = n0 >> 10;
  int c0 = n0 & 1023;
  bf16* outp = (f == 0) ? xrg : (f == 1) ? xwa : (f == 2) ? xk : xv;
  int ocol = c0 + fr;
  int orow0 = m0 + (wv << 5) + (fq << 2);
#define WRA(accv, mf, nt) { int cc = ocol + ((nt) << 4); \
    float ta = tmaa[(f << 10) + cc]; \
    _Pragma("unroll") for (int r = 0; r < 4; r++) { \
      int row = orow0 + ((mf) << 4) + r; \
      int t = row & (T_ - 1); \
      long xo = (long)row * C_ + cc; \
      float xb = x[xo]; \
      float xq = (t > 0) ? x[xo - C_] : 0.0f; \
      outp[xo] = f2bf(fmaf(xq - xb, ta + accv[r], xb)); } }
  WRA(a00, 0, 0) WRA(a01, 0, 1) WRA(a02, 0, 2) WRA(a03, 0, 3)
  WRA(a10, 1, 0) WRA(a11, 1, 1) WRA(a12, 1, 2) WRA(a13, 1, 3)
#undef WRA
}

// ---------------- K5: fuse2-lite (pure elementwise; dots via GEMM) ----------
// d2[m][j*1024+c] = {wd, ad, mad, kkd, mkd} fp32 from the w2e5 GEMM.
// R11 lesson: folding this into the scan's staging path serializes the
// transcendental chain into the scan's critical path (1 wave/SIMD, in-order)
// AND scatters the d2 reads -- scan went 128->299us. Standalone it's ~15us.
__global__ __launch_bounds__(256) void fuse2_kernel(
    const float* __restrict__ kraw, const float* __restrict__ d2,
    const float* __restrict__ tdec, const float* __restrict__ taa,
    const float* __restrict__ tma, const float* __restrict__ tmk,
    float* __restrict__ ew, float* __restrict__ kfin,
    float* __restrict__ kkn, float* __restrict__ bbo) {
  int m = blockIdx.x, tid = threadIdx.x;
  int c4 = tid << 2;
  const float* dp = d2 + (long)m * 5120;
  float4 wd4 = *(const float4*)(dp + c4);
  float4 ad4 = *(const float4*)(dp + 1024 + c4);
  float4 mad4 = *(const float4*)(dp + 2048 + c4);
  float4 kd4 = *(const float4*)(dp + 3072 + c4);
  float4 mkd4 = *(const float4*)(dp + 4096 + c4);
  float4 kraw4 = *(const float4*)(kraw + (long)m * C_ + c4);
  float4 tdec4 = *(const float4*)(tdec + c4);
  float4 taa4 = *(const float4*)(taa + c4);
  float4 tma4 = *(const float4*)(tma + c4);
  float4 tmk4 = *(const float4*)(tmk + c4);
  float wd[4] = {wd4.x, wd4.y, wd4.z, wd4.w};
  float ad[4] = {ad4.x, ad4.y, ad4.z, ad4.w};
  float mad[4] = {mad4.x, mad4.y, mad4.z, mad4.w};
  float kd[4] = {kd4.x, kd4.y, kd4.z, kd4.w};
  float mkd[4] = {mkd4.x, mkd4.y, mkd4.z, mkd4.w};
  float krw[4] = {kraw4.x, kraw4.y, kraw4.z, kraw4.w};
  float td[4] = {tdec4.x, tdec4.y, tdec4.z, tdec4.w};
  float ta[4] = {taa4.x, taa4.y, taa4.z, taa4.w};
  float tm[4] = {tma4.x, tma4.y, tma4.z, tma4.w};
  float tk[4] = {tmk4.x, tmk4.y, tmk4.z, tmk4.w};
  float kkp[4], av[4], wvv[4], kr[4], mkv[4];
  float sumsq = 0.f;
#pragma unroll
  for (int j = 0; j < 4; j++) {
    float w = -softplusf_(-(td[j] + wd[j])) - 0.5f;
    wvv[j] = w;
    float kkpre = krw[j] + kd[j];
    kkp[j] = kkpre;
    sumsq += kkpre * kkpre;
    float a = sigmoidf_(ta[j] + ad[j]);
    av[j] = a;
    float ma = sigmoidf_(tm[j] + mad[j]);
    float mk = sigmoidf_(tk[j] + mkd[j]);
    mkv[j] = mk;
    kr[j] = krw[j] * (ma + a * (1.f - ma));
  }
  sumsq += __shfl_xor(sumsq, 1);
  sumsq += __shfl_xor(sumsq, 2);
  sumsq += __shfl_xor(sumsq, 4);
  sumsq += __shfl_xor(sumsq, 8);
  float rn = 1.0f / fmaxf(sqrtf(sumsq), 1e-12f);
  float4 kknv, bbov, eww, kfv;
  float* kknp = (float*)&kknv;
  float* bbop = (float*)&bbov;
  float* ewp = (float*)&eww;
  float* kfp = (float*)&kfv;
#pragma unroll
  for (int j = 0; j < 4; j++) {
    float kkx = kkp[j] * rn;
    kknp[j] = kkx;
    bbop[j] = -kkx * av[j];
    ewp[j] = expf(wvv[j]);
    kfp[j] = kr[j] * expf(wvv[j] * mkv[j]);
  }
  long off4 = (long)m * C_ + c4;
  *(float4*)(kkn + off4) = kknv;
  *(float4*)(bbo + off4) = bbov;
  *(float4*)(ew + off4) = eww;
  *(float4*)(kfin + off4) = kfv;
}

// ---------------- K6: RWKV-7 scan, 128 blocks x 256 threads -----------------
// R3 structure (dbuf LDS, 3-set rotating register pipeline, sched_barrier) +
// R7 y-pipeline (qsum16x2 overlaps token t's sab chain with t-1's y chain).
// ~300 cyc/token floor; resisted packing/scheduling/interleave changes (R3,
// R4, R7) AND the R11 fuse2-fold regressed 2.3x -- keep this form.
#define SCHUNK 16
#define NCHUNK (T_ / SCHUNK)
__global__ __launch_bounds__(256, 1) void scan_kernel(
    const float* __restrict__ rB, const float* __restrict__ ewB,
    const float* __restrict__ kB, const float* __restrict__ vB,
    const float* __restrict__ kkB, const float* __restrict__ bbB,
    float* __restrict__ yB) {
  __shared__ __align__(16) float lds[2][6][SCHUNK * 64];
  int bid = blockIdx.x;          // 0..127
  int bh = bid >> 2, rg = bid & 3;
  int b = bh >> 4, h = bh & 15;
  int tid = threadIdx.x;
  int wave = tid >> 6, lane = tid & 63;
  int g = lane >> 4, q = lane & 15;
  int row = (rg << 4) + (wave << 2) + g;
  int kq = q << 2;
  const long base = ((long)b * T_) * C_ + (h << 6);
  const float* s0 = kkB + base;
  const float* s1 = ewB + base;
  const float* s2 = kB + base;
  const float* s3 = bbB + base;
  const float* s4 = rB + base;
  const float* s5 = vB + base;
  int stok = tid >> 4;
  int spc = (tid & 15) << 2;
  int lo = (stok << 6) + spc;
  float4 rb0, rb1, rb2, rb3, rb4, rb5;
  auto loadc = [&](int c) {
    long go = (long)((c << 4) + stok) * C_ + spc;
    rb0 = *(const float4*)(s0 + go);
    rb1 = *(const float4*)(s1 + go);
    rb2 = *(const float4*)(s2 + go);
    rb3 = *(const float4*)(s3 + go);
    rb4 = *(const float4*)(s4 + go);
    rb5 = *(const float4*)(s5 + go);
  };
  auto stage = [&](int buf) {
    *(float4*)&lds[buf][0][lo] = rb0;
    *(float4*)&lds[buf][1][lo] = rb1;
    *(float4*)&lds[buf][2][lo] = rb2;
    *(float4*)&lds[buf][3][lo] = rb3;
    *(float4*)&lds[buf][4][lo] = rb4;
    *(float4*)&lds[buf][5][lo] = rb5;
  };
  float S0 = 0.f, S1 = 0.f, S2 = 0.f, S3 = 0.f;
  float ypv = 0.f;
  float4 Q0kk, Q0ew, Q0k, Q0bb, Q0r; float Q0v;
  float4 Q1kk, Q1ew, Q1k, Q1bb, Q1r; float Q1v;
  float4 Q2kk, Q2ew, Q2k, Q2bb, Q2r; float Q2v;

#define PF(i, tt) { int tb_ = ((tt) << 6); \
    Q##i##kk = *(const float4*)&lds[cur][0][tb_ + kq]; \
    Q##i##ew = *(const float4*)&lds[cur][1][tb_ + kq]; \
    Q##i##k  = *(const float4*)&lds[cur][2][tb_ + kq]; \
    Q##i##bb = *(const float4*)&lds[cur][3][tb_ + kq]; \
    Q##i##r  = *(const float4*)&lds[cur][4][tb_ + kq]; \
    Q##i##v  = lds[cur][5][tb_ + row]; }
#define SBAR __builtin_amdgcn_sched_barrier(0x7)
#define ST(i, gtok, FIRSTT) { \
    float p_ = fmaf(S1, Q##i##kk.y, S0 * Q##i##kk.x) + \
               fmaf(S3, Q##i##kk.w, S2 * Q##i##kk.z); \
    float yo_ = ypv; \
    qsum16x2(p_, yo_); \
    if (q == 0 && !((FIRSTT) && c == 0)) \
      yB[base + (long)((gtok) - 1) * C_ + row] = yo_; \
    float n0 = fmaf(S0, Q##i##ew.x, Q##i##v * Q##i##k.x); \
    float n1 = fmaf(S1, Q##i##ew.y, Q##i##v * Q##i##k.y); \
    float n2 = fmaf(S2, Q##i##ew.z, Q##i##v * Q##i##k.z); \
    float n3 = fmaf(S3, Q##i##ew.w, Q##i##v * Q##i##k.w); \
    S0 = fmaf(p_, Q##i##bb.x, n0); \
    S1 = fmaf(p_, Q##i##bb.y, n1); \
    S2 = fmaf(p_, Q##i##bb.z, n2); \
    S3 = fmaf(p_, Q##i##bb.w, n3); \
    ypv = fmaf(S1, Q##i##r.y, S0 * Q##i##r.x) + \
          fmaf(S3, Q##i##r.w, S2 * Q##i##r.z); }

  loadc(0);
  stage(0);
  loadc(1);
  __syncthreads();
  int cur = 0;
  for (int c = 0; c < NCHUNK; c++) {
    int t0 = c << 4;
    PF(0, 0); PF(1, 1);
    if (c + 1 < NCHUNK) stage(cur ^ 1);
    if (c + 2 < NCHUNK) loadc(c + 2);
    SBAR;
    PF(2, 2);  SBAR; ST(0, t0 + 0, true);
    PF(0, 3);  SBAR; ST(1, t0 + 1, false);
    PF(1, 4);  SBAR; ST(2, t0 + 2, false);
    PF(2, 5);  SBAR; ST(0, t0 + 3, false);
    PF(0, 6);  SBAR; ST(1, t0 + 4, false);
    PF(1, 7);  SBAR; ST(2, t0 + 5, false);
    PF(2, 8);  SBAR; ST(0, t0 + 6, false);
    PF(0, 9);  SBAR; ST(1, t0 + 7, false);
    PF(1, 10); SBAR; ST(2, t0 + 8, false);
    PF(2, 11); SBAR; ST(0, t0 + 9, false);
    PF(0, 12); SBAR; ST(1, t0 + 10, false);
    PF(1, 13); SBAR; ST(2, t0 + 11, false);
    PF(2, 14); SBAR; ST(0, t0 + 12, false);
    PF(0, 15); SBAR; ST(1, t0 + 13, false);
    ST(2, t0 + 14, false);
    ST(0, t0 + 15, false);
    __syncthreads();
    cur ^= 1;
  }
  {
    float yo = qsum16(ypv);
    if (q == 0) yB[base + (long)(T_ - 1) * C_ + row] = yo;
  }
#undef PF
#undef SBAR
#undef ST
}

// ---------------- K7: GroupNorm + bonus + gate (bf16 out) -------------------
__global__ __launch_bounds__(256) void gnout_kernel(
    const float* __restrict__ y, const float* __restrict__ r,
    const float* __restrict__ kf, const float* __restrict__ v,
    const float* __restrict__ g,
    const float* __restrict__ lnw, const float* __restrict__ lnb,
    const float* __restrict__ fa, bf16* __restrict__ z) {
  int tid = threadIdx.x;
  int w = tid >> 6, lane = tid & 63;
  int gi = (blockIdx.x << 2) + w;
  int h = gi & 15, mt = gi >> 4;
  long off = (long)mt * C_ + (h << 6) + lane;
  float yv = y[off];
  float s = yv;
  s += __shfl_xor(s, 1); s += __shfl_xor(s, 2); s += __shfl_xor(s, 4);
  s += __shfl_xor(s, 8); s += __shfl_xor(s, 16); s += __shfl_xor(s, 32);
  float mu = s * (1.0f / 64.0f);
  float d = yv - mu;
  float s2 = d * d;
  s2 += __shfl_xor(s2, 1); s2 += __shfl_xor(s2, 2); s2 += __shfl_xor(s2, 4);
  s2 += __shfl_xor(s2, 8); s2 += __shfl_xor(s2, 16); s2 += __shfl_xor(s2, 32);
  float var = s2 * (1.0f / 64.0f);
  int hc = (h << 6) + lane;
  float dot = r[off] * kf[off] * fa[hc];
  dot += __shfl_xor(dot, 1); dot += __shfl_xor(dot, 2); dot += __shfl_xor(dot, 4);
  dot += __shfl_xor(dot, 8); dot += __shfl_xor(dot, 16); dot += __shfl_xor(dot, 32);
  float yn = d * rsqrtf(var + 0.00064f) * lnw[hc] + lnb[hc];
  z[off] = f2bf((yn + dot * v[off]) * g[off]);
}

extern "C" void kernel_launch(void* const* d_in, const int* in_sizes, int n_in,
                              void* d_out, int out_size, void* d_ws, size_t ws_size,
                              hipStream_t stream) {
  const float* x = (const float*)d_in[0];
  const float* tmx = (const float*)d_in[1];
  const float* tmaa = (const float*)d_in[2];
  const float* tmw1 = (const float*)d_in[3];
  const float* tmw2 = (const float*)d_in[4];
  const float* tdec = (const float*)d_in[5];
  const float* tdw1 = (const float*)d_in[6];
  const float* tdw2 = (const float*)d_in[7];
  const float* taa5 = (const float*)d_in[8];
  const float* taw1 = (const float*)d_in[9];
  const float* taw2 = (const float*)d_in[10];
  const float* tkw1 = (const float*)d_in[11];
  const float* tkw2 = (const float*)d_in[12];
  const float* gw1 = (const float*)d_in[13];
  const float* gw2 = (const float*)d_in[14];
  const float* tmia = (const float*)d_in[15];
  const float* maw1 = (const float*)d_in[16];
  const float* maw2 = (const float*)d_in[17];
  const float* tmik = (const float*)d_in[18];
  const float* mkw1 = (const float*)d_in[19];
  const float* mkw2 = (const float*)d_in[20];
  const float* wrec = (const float*)d_in[21];
  const float* wkey = (const float*)d_in[22];
  const float* wval = (const float*)d_in[23];
  const float* wout = (const float*)d_in[24];
  const float* lnw = (const float*)d_in[25];
  const float* lnb = (const float*)d_in[26];
  const float* faaa = (const float*)d_in[27];

  const long MT = 2048, CC = 1024;
  char* base = (char*)d_ws;
  float* y = (float*)base;     base += MT * CC * 4;
  bf16* xrgb = (bf16*)base;    base += MT * CC * 2;   // ┐ kfin overlays (8MB)
  bf16* xwab = (bf16*)base;    base += MT * CC * 2;   // ┘
  bf16* xkb = (bf16*)base;     base += MT * CC * 2;   // ┐ kkn overlays (8MB)
  bf16* xvb = (bf16*)base;     base += MT * CC * 2;   // ┘
  float* rr = (float*)base;    base += MT * CC * 4;
  float* kraw = (float*)base;  base += MT * CC * 4;   // also ew
  float* vv = (float*)base;    base += MT * CC * 4;
  float* gg = (float*)base;    base += MT * CC * 4;
  float* bbo = (float*)base;   base += MT * CC * 4;
  bf16* g1b = (bf16*)base;     base += MT * 128 * 2;
  bf16* out12b = (bf16*)base;  base += MT * 128 * 2;  // [w1|a1|ma1|kk1|mk1]
  bf16* zb = (bf16*)base;      base += MT * CC * 2;
  bf16* mixb = (bf16*)base;    base += MT * 128 * 2;
  float* d2 = (float*)base;    base += MT * 5120L * 4; // fuse2 dots (fp32)
  bf16* tmw1b = (bf16*)base;   base += 128 * CC * 2;
  bf16* wrecb = (bf16*)base;   base += CC * CC * 2;
  bf16* gw1b = (bf16*)base;    base += 128 * CC * 2;
  bf16* gw2b = (bf16*)base;    base += CC * 128 * 2;
  bf16* wkeyb = (bf16*)base;   base += CC * CC * 2;
  bf16* wvalb = (bf16*)base;   base += CC * CC * 2;
  bf16* woutb = (bf16*)base;   base += CC * CC * 2;
  bf16* wskb = (bf16*)base;    base += 32 * CC * 2;
  bf16* wswab = (bf16*)base;   base += 96 * CC * 2;
  bf16* tmw2e = (bf16*)base;   base += 4096L * 128 * 2;
  bf16* w2e5b = (bf16*)base;   base += 5120L * 128 * 2;
  // aliases (dead-buffer reuse, verified non-overlapping in time):
  float* ew = kraw;            // fuse2 reads kraw then writes ew at same offs
  float* kfin = (float*)xrgb;  // xrg/xwa bf16 dead before fuse2
  float* kkn = (float*)xkb;    // xk/xv bf16 dead before fuse2

  // one launch: all conversions/expansions + the mix GEMM (raw-f32 W staging)
  cvt_mix_kernel<<<5792, 256, 0, stream>>>(
      tmw1, wrec, gw1, gw2, wkey, wval, wout,
      tmw1b, wrecb, gw1b, gw2b, wkeyb, wvalb, woutb,
      tkw1, mkw1, tdw1, taw1, maw1, wskb, wswab,
      tmw2, tdw2, tkw2, taw2, maw2, mkw2,
      tmw2e, w2e5b, x, tmx, mixb);

  // deltas GEMM with fused mix-apply epilogue -> xrg/xwa/xk/xv
  gemm_mixapply_kernel<<<dim3(64, 16), 256, 0, stream>>>(
      mixb, tmw2e, x, tmaa, xrgb, xwab, xkb, xvb);
  // 6 independent K=1024 GEMMs, one launch; z=3/z=5 write slices of out12b
  {
    GemmBatch gb = {};
    gb.A[0] = xrgb; gb.W[0] = wrecb; gb.Cf[0] = rr;      gb.Cb[0] = nullptr; gb.N[0] = 1024; gb.actN[0] = 0;   gb.ldc[0] = 1024; gb.coff[0] = 0;
    gb.A[1] = xrgb; gb.W[1] = gw1b;  gb.Cf[1] = nullptr; gb.Cb[1] = g1b;     gb.N[1] = 128;  gb.actN[1] = 128; gb.ldc[1] = 128;  gb.coff[1] = 0;
    gb.A[2] = xkb;  gb.W[2] = wkeyb; gb.Cf[2] = kraw;    gb.Cb[2] = nullptr; gb.N[2] = 1024; gb.actN[2] = 0;   gb.ldc[2] = 1024; gb.coff[2] = 0;
    gb.A[3] = xkb;  gb.W[3] = wskb;  gb.Cf[3] = nullptr; gb.Cb[3] = out12b;  gb.N[3] = 32;   gb.actN[3] = 16;  gb.ldc[3] = 128;  gb.coff[3] = 96;
    gb.A[4] = xvb;  gb.W[4] = wvalb; gb.Cf[4] = vv;      gb.Cb[4] = nullptr; gb.N[4] = 1024; gb.actN[4] = 0;   gb.ldc[4] = 1024; gb.coff[4] = 0;
    gb.A[5] = xwab; gb.W[5] = wswab; gb.Cf[5] = nullptr; gb.Cb[5] = out12b;  gb.N[5] = 96;   gb.actN[5] = 64;  gb.ldc[5] = 128;  gb.coff[5] = 0;
    gemm_batch_kernel<<<dim3(16, 16, 6), 256, 0, stream>>>(gb, 1024);
  }
  // batch2 (K=128): gg GEMM + fuse2-dots GEMM (d2 = out12b x w2e5^T, fp32)
  {
    GemmBatch gb = {};
    gb.A[0] = g1b;    gb.W[0] = gw2b;  gb.Cf[0] = gg; gb.Cb[0] = nullptr; gb.N[0] = 1024; gb.actN[0] = 0; gb.ldc[0] = 1024; gb.coff[0] = 0;
    gb.A[1] = out12b; gb.W[1] = w2e5b; gb.Cf[1] = d2; gb.Cb[1] = nullptr; gb.N[1] = 5120; gb.actN[1] = 0; gb.ldc[1] = 5120; gb.coff[1] = 0;
    gemm_batch_kernel<<<dim3(80, 16, 2), 256, 0, stream>>>(gb, 128);
  }
  fuse2_kernel<<<2048, 256, 0, stream>>>(kraw, d2, tdec, taa5, tmia, tmik,
                                         ew, kfin, kkn, bbo);
  scan_kernel<<<128, 256, 0, stream>>>(rr, ew, kfin, vv, kkn, bbo, y);
  gnout_kernel<<<8192, 256, 0, stream>>>(y, rr, kfin, vv, gg, lnw, lnb, faaa, zb);
  // output GEMM: (2048x1024)x(1024x1024)^T
  {
    GemmBatch gb = {};
    gb.A[0] = zb; gb.W[0] = woutb; gb.Cf[0] = (float*)d_out; gb.Cb[0] = nullptr;
    gb.N[0] = 1024; gb.actN[0] = 0; gb.ldc[0] = 1024; gb.coff[0] = 0;
    gemm_batch_kernel<<<dim3(16, 16, 1), 256, 0, stream>>>(gb, 1024);
  }
}

// Round 13
// 421.951 us; speedup vs baseline: 1.3669x; 1.0116x over previous
//
#include <hip/hip_runtime.h>
#include <hip/hip_bf16.h>

typedef __hip_bfloat16 bf16;

#define B_ 2
#define T_ 1024
#define C_ 1024
#define H_ 16
#define N_ 64

using short4v = __attribute__((ext_vector_type(4))) short;
using short8 = __attribute__((ext_vector_type(8))) short;
using f32x4 = __attribute__((ext_vector_type(4))) float;

__device__ __forceinline__ float bs2f(short s) {
  return __uint_as_float(((unsigned int)(unsigned short)s) << 16);
}
__device__ __forceinline__ bf16 f2bf(float f) { return __float2bfloat16(f); }
__device__ __forceinline__ short bfbits(float f) {
  bf16 h = __float2bfloat16(f);
  return *reinterpret_cast<short*>(&h);
}
__device__ __forceinline__ float sigmoidf_(float x) { return 1.0f / (1.0f + expf(-x)); }
__device__ __forceinline__ float softplusf_(float x) {
  return fmaxf(x, 0.0f) + log1pf(expf(-fabsf(x)));
}
// Async global->LDS, 16B per lane: LDS dest = wave-uniform base + lane*16;
// global source is per-lane. __syncthreads() drains vmcnt before reads.
__device__ __forceinline__ void gload16(const bf16* g, bf16* l) {
  __builtin_amdgcn_global_load_lds(
      (const __attribute__((address_space(1))) unsigned int*)g,
      (__attribute__((address_space(3))) unsigned int*)l, 16, 0, 0);
}
// Full 16-lane-row sum, all lanes receive the result. Pure-VALU DPP.
__device__ __forceinline__ float qsum16(float x) {
  int a = __builtin_amdgcn_update_dpp(0, __float_as_int(x), 0xB1, 0xF, 0xF, true);
  x += __int_as_float(a);
  int b = __builtin_amdgcn_update_dpp(0, __float_as_int(x), 0x4E, 0xF, 0xF, true);
  x += __int_as_float(b);
  int c = __builtin_amdgcn_update_dpp(0, __float_as_int(x), 0x124, 0xF, 0xF, true);
  x += __int_as_float(c);
  int d = __builtin_amdgcn_update_dpp(0, __float_as_int(x), 0x128, 0xF, 0xF, true);
  x += __int_as_float(d);
  return x;
}
// Two interleaved 16-lane-row sums (overlaps token t's sab chain with token
// t-1's y chain; see scan_kernel comment).
__device__ __forceinline__ void qsum16x2(float& x, float& y) {
  int a0 = __builtin_amdgcn_update_dpp(0, __float_as_int(x), 0xB1, 0xF, 0xF, true);
  int b0 = __builtin_amdgcn_update_dpp(0, __float_as_int(y), 0xB1, 0xF, 0xF, true);
  x += __int_as_float(a0); y += __int_as_float(b0);
  int a1 = __builtin_amdgcn_update_dpp(0, __float_as_int(x), 0x4E, 0xF, 0xF, true);
  int b1 = __builtin_amdgcn_update_dpp(0, __float_as_int(y), 0x4E, 0xF, 0xF, true);
  x += __int_as_float(a1); y += __int_as_float(b1);
  int a2 = __builtin_amdgcn_update_dpp(0, __float_as_int(x), 0x124, 0xF, 0xF, true);
  int b2 = __builtin_amdgcn_update_dpp(0, __float_as_int(y), 0x124, 0xF, 0xF, true);
  x += __int_as_float(a2); y += __int_as_float(b2);
  int a3 = __builtin_amdgcn_update_dpp(0, __float_as_int(x), 0x128, 0xF, 0xF, true);
  int b3 = __builtin_amdgcn_update_dpp(0, __float_as_int(y), 0x128, 0xF, 0xF, true);
  x += __int_as_float(a3); y += __int_as_float(b3);
}

// ---------------- K0: cvt + expansions + mix-GEMM, ONE launch ---------------
__global__ __launch_bounds__(256) void cvt_mix_kernel(
    const float* __restrict__ s0, const float* __restrict__ s1,
    const float* __restrict__ s2, const float* __restrict__ s3,
    const float* __restrict__ s4, const float* __restrict__ s5,
    const float* __restrict__ s6,
    bf16* __restrict__ d0, bf16* __restrict__ d1, bf16* __restrict__ d2w,
    bf16* __restrict__ d3, bf16* __restrict__ d4, bf16* __restrict__ d5,
    bf16* __restrict__ d6,
    const float* __restrict__ tkw1, const float* __restrict__ mkw1,
    const float* __restrict__ tdw1, const float* __restrict__ taw1,
    const float* __restrict__ maw1,
    bf16* __restrict__ wsk, bf16* __restrict__ wswa,
    const float* __restrict__ tmw2, const float* __restrict__ tdw2,
    const float* __restrict__ tkw2, const float* __restrict__ taw2,
    const float* __restrict__ maw2, const float* __restrict__ mkw2,
    bf16* __restrict__ tmw2e, bf16* __restrict__ w2e5,
    const float* __restrict__ x, const float* __restrict__ tmx,
    bf16* __restrict__ mixb) {
  long bidx = blockIdx.x;
  if (bidx >= 5760) {                     // -------- mix GEMM blocks --------
    __shared__ __align__(16) bf16 As[128][72];
    __shared__ __align__(16) bf16 Ws[64][72];
    const int K = 1024;
    int mb = (int)(bidx - 5760);
    int n0 = (mb & 1) << 6;
    int m0 = (mb >> 1) << 7;
    int tid = threadIdx.x;
    int arow = tid >> 1, acol = (tid & 1) << 5;
    int wrow = tid >> 2, wcol = (tid & 3) << 4;
    int wv = tid >> 6, lane = tid & 63;
    int fr = lane & 15, fq = lane >> 4;
    int grow = m0 + arow;
    int t = grow & (T_ - 1);
    const float* xp = x + (long)grow * C_ + acol;
    const float* Wp = s0 + (long)(n0 + wrow) * K + wcol;  // raw f32 tmw1
    f32x4 a00 = {0.f, 0.f, 0.f, 0.f};
    f32x4 a01 = a00, a02 = a00, a03 = a00, a10 = a00, a11 = a00, a12 = a00, a13 = a00;
    for (int k0 = 0; k0 < K; k0 += 64) {
#pragma unroll
      for (int jj = 0; jj < 4; jj++) {
        int co = k0 + (jj << 3);
        float4 c0 = *(const float4*)(xp + co);
        float4 c1 = *(const float4*)(xp + co + 4);
        float4 q0 = {0.f, 0.f, 0.f, 0.f}, q1 = q0;
        if (t > 0) {
          q0 = *(const float4*)(xp + co - C_);
          q1 = *(const float4*)(xp + co + 4 - C_);
        }
        float4 m0v = *(const float4*)(tmx + co + acol);
        float4 m1v = *(const float4*)(tmx + co + acol + 4);
        short8 sv;
        sv[0] = bfbits(fmaf(q0.x - c0.x, m0v.x, c0.x));
        sv[1] = bfbits(fmaf(q0.y - c0.y, m0v.y, c0.y));
        sv[2] = bfbits(fmaf(q0.z - c0.z, m0v.z, c0.z));
        sv[3] = bfbits(fmaf(q0.w - c0.w, m0v.w, c0.w));
        sv[4] = bfbits(fmaf(q1.x - c1.x, m1v.x, c1.x));
        sv[5] = bfbits(fmaf(q1.y - c1.y, m1v.y, c1.y));
        sv[6] = bfbits(fmaf(q1.z - c1.z, m1v.z, c1.z));
        sv[7] = bfbits(fmaf(q1.w - c1.w, m1v.w, c1.w));
        *(short8*)&As[arow][acol + (jj << 3)] = sv;
      }
      {
        float4 w0 = *(const float4*)(Wp + k0);
        float4 w1 = *(const float4*)(Wp + k0 + 4);
        float4 w2 = *(const float4*)(Wp + k0 + 8);
        float4 w3 = *(const float4*)(Wp + k0 + 12);
        short8 wv0, wv1;
        wv0[0] = bfbits(w0.x); wv0[1] = bfbits(w0.y); wv0[2] = bfbits(w0.z); wv0[3] = bfbits(w0.w);
        wv0[4] = bfbits(w1.x); wv0[5] = bfbits(w1.y); wv0[6] = bfbits(w1.z); wv0[7] = bfbits(w1.w);
        wv1[0] = bfbits(w2.x); wv1[1] = bfbits(w2.y); wv1[2] = bfbits(w2.z); wv1[3] = bfbits(w2.w);
        wv1[4] = bfbits(w3.x); wv1[5] = bfbits(w3.y); wv1[6] = bfbits(w3.z); wv1[7] = bfbits(w3.w);
        *(short8*)&Ws[wrow][wcol] = wv0;
        *(short8*)&Ws[wrow][wcol + 8] = wv1;
      }
      __syncthreads();
#pragma unroll
      for (int kk = 0; kk < 2; kk++) {
        int ko = (fq << 3) + (kk << 5);
        short8 af0 = *(const short8*)&As[(wv << 5) + fr][ko];
        short8 af1 = *(const short8*)&As[(wv << 5) + 16 + fr][ko];
        short8 b0 = *(const short8*)&Ws[fr][ko];
        short8 b1 = *(const short8*)&Ws[16 + fr][ko];
        short8 b2 = *(const short8*)&Ws[32 + fr][ko];
        short8 b3 = *(const short8*)&Ws[48 + fr][ko];
        a00 = __builtin_amdgcn_mfma_f32_16x16x32_bf16(af0, b0, a00, 0, 0, 0);
        a01 = __builtin_amdgcn_mfma_f32_16x16x32_bf16(af0, b1, a01, 0, 0, 0);
        a02 = __builtin_amdgcn_mfma_f32_16x16x32_bf16(af0, b2, a02, 0, 0, 0);
        a03 = __builtin_amdgcn_mfma_f32_16x16x32_bf16(af0, b3, a03, 0, 0, 0);
        a10 = __builtin_amdgcn_mfma_f32_16x16x32_bf16(af1, b0, a10, 0, 0, 0);
        a11 = __builtin_amdgcn_mfma_f32_16x16x32_bf16(af1, b1, a11, 0, 0, 0);
        a12 = __builtin_amdgcn_mfma_f32_16x16x32_bf16(af1, b2, a12, 0, 0, 0);
        a13 = __builtin_amdgcn_mfma_f32_16x16x32_bf16(af1, b3, a13, 0, 0, 0);
      }
      __syncthreads();
    }
    const int Nz = 128;
    int ocol = n0 + fr;
    int orow0 = m0 + (wv << 5) + (fq << 2);
#define WRM(accv, mf, nt) { int col = ocol + ((nt) << 4); \
    _Pragma("unroll") for (int r = 0; r < 4; r++) { \
      long oi = (long)(orow0 + ((mf) << 4) + r) * Nz + col; \
      mixb[oi] = f2bf(tanhf(accv[r])); } }
    WRM(a00, 0, 0) WRM(a01, 0, 1) WRM(a02, 0, 2) WRM(a03, 0, 3)
    WRM(a10, 1, 0) WRM(a11, 1, 1) WRM(a12, 1, 2) WRM(a13, 1, 3)
#undef WRM
    return;
  }
  const float* s; bf16* d; long off;
  if (bidx < 4480) {                      // big weights
    long i4 = bidx * 256 + threadIdx.x;
    if (i4 < 32768) { s = s0; d = d0; off = i4; }
    else if (i4 < 294912) { s = s1; d = d1; off = i4 - 32768; }
    else if (i4 < 327680) { s = s2; d = d2w; off = i4 - 294912; }
    else if (i4 < 360448) { s = s3; d = d3; off = i4 - 327680; }
    else if (i4 < 622592) { s = s4; d = d4; off = i4 - 360448; }
    else if (i4 < 884736) { s = s5; d = d5; off = i4 - 622592; }
    else { s = s6; d = d6; off = i4 - 884736; }
  } else if (bidx < 4608) {               // LoRA-1 packs
    long i4 = (bidx - 4480) * 256 + threadIdx.x;  // < 32768
    long so, dof;
    if (i4 < 4096) { s = tkw1; so = i4; d = wsk; dof = i4; }
    else if (i4 < 8192) { s = mkw1; so = i4 - 4096; d = wsk; dof = i4; }
    else if (i4 < 24576) { s = tdw1; so = i4 - 8192; d = wswa; dof = i4 - 8192; }
    else if (i4 < 28672) { s = taw1; so = i4 - 24576; d = wswa; dof = i4 - 8192; }
    else { s = maw1; so = i4 - 28672; d = wswa; dof = i4 - 8192; }
    float4 v = *(const float4*)(s + so * 4);
    d[dof * 4 + 0] = f2bf(v.x); d[dof * 4 + 1] = f2bf(v.y);
    d[dof * 4 + 2] = f2bf(v.z); d[dof * 4 + 3] = f2bf(v.w);
    return;
  } else if (bidx < 5120) {               // tmw2e expansion (4096x128)
    long i4 = (bidx - 4608) * 256 + threadIdx.x;  // < 131072
    long n = i4 >> 5;
    int k0 = (int)(i4 & 31) << 2;
    int f = (int)(n >> 10);
    float4 v = {0.f, 0.f, 0.f, 0.f};
    if ((k0 >> 5) == f) v = *(const float4*)(tmw2 + n * 32 + (k0 & 31));
    tmw2e[i4 * 4 + 0] = f2bf(v.x);
    tmw2e[i4 * 4 + 1] = f2bf(v.y);
    tmw2e[i4 * 4 + 2] = f2bf(v.z);
    tmw2e[i4 * 4 + 3] = f2bf(v.w);
    return;
  } else {                                // w2e5 expansion (5120x128)
    long i4 = (bidx - 5120) * 256 + threadIdx.x;  // < 163840
    long rowi = i4 >> 5;                  // 0..5119
    int k0 = (int)(i4 & 31) << 2;         // 0..124
    int j = (int)(rowi >> 10);
    int c = (int)(rowi & 1023);
    float4 v = {0.f, 0.f, 0.f, 0.f};
    if (j == 0) { if (k0 < 64) v = *(const float4*)(tdw2 + c * 64 + k0); }
    else if (j == 1) { if (k0 >= 64 && k0 < 80) v = *(const float4*)(taw2 + c * 16 + (k0 - 64)); }
    else if (j == 2) { if (k0 >= 80 && k0 < 96) v = *(const float4*)(maw2 + c * 16 + (k0 - 80)); }
    else if (j == 3) { if (k0 >= 96 && k0 < 112) v = *(const float4*)(tkw2 + c * 16 + (k0 - 96)); }
    else { if (k0 >= 112) v = *(const float4*)(mkw2 + c * 16 + (k0 - 112)); }
    w2e5[i4 * 4 + 0] = f2bf(v.x);
    w2e5[i4 * 4 + 1] = f2bf(v.y);
    w2e5[i4 * 4 + 2] = f2bf(v.z);
    w2e5[i4 * 4 + 3] = f2bf(v.w);
    return;
  }
  float4 v = *(const float4*)(s + off * 4);
  d[off * 4 + 0] = f2bf(v.x);
  d[off * 4 + 1] = f2bf(v.y);
  d[off * 4 + 2] = f2bf(v.z);
  d[off * 4 + 3] = f2bf(v.w);
}

// ---------------- Batched MFMA GEMM: C[z] = A[z] * W[z]^T -------------------
// R13: linear LDS (no +8 padding) + global_load_lds(16B) staging -- the
// documented biggest lever for the 2-barrier K-loop (m151: 646->874 TF).
// Bank conflicts from linear rows are hidden at this structure (m233: the
// stage+vmcnt+barrier is ~72% of critical path). Partial W tiles (N<64
// remainder) fall back to reg-staging with zero fill.
struct GemmBatch {
  const bf16* A[6]; const bf16* W[6];
  float* Cf[6]; bf16* Cb[6];
  int N[6]; int actN[6]; int ldc[6]; int coff[6];
};

__global__ __launch_bounds__(256) void gemm_batch_kernel(GemmBatch gb, int K) {
  __shared__ __align__(16) bf16 As[128][64];
  __shared__ __align__(16) bf16 Ws[64][64];
  int z = blockIdx.z;
  int Nz = gb.N[z];
  int n0 = blockIdx.x << 6;
  if (n0 >= Nz) return;
  int m0 = blockIdx.y << 7;
  int actN = gb.actN[z];
  int ldc = gb.ldc[z], coff = gb.coff[z];
  const bf16* A = gb.A[z];
  const bf16* W = gb.W[z];
  float* Cf = gb.Cf[z];
  bf16* Cb = gb.Cb[z];
  int tid = threadIdx.x;
  int wrow = tid >> 2, wcol = (tid & 3) << 4;   // fallback W staging coords
  int wv = tid >> 6, lane = tid & 63;
  int fr = lane & 15, fq = lane >> 4;
  int lrow = lane >> 3, lcol = (lane & 7) << 3; // gload lane coords (8 rows/inst)
  bool wok = (n0 + wrow) < Nz;
  bool fullW = (n0 + 64 <= Nz);
  const bf16* Ag = A + (long)m0 * K;
  const bf16* Wg = W + (long)n0 * K;
  const bf16* Wp = W + (long)(n0 + wrow) * K + wcol;
  short8 zz = {0, 0, 0, 0, 0, 0, 0, 0};
  f32x4 a00 = {0.f, 0.f, 0.f, 0.f};
  f32x4 a01 = a00, a02 = a00, a03 = a00, a10 = a00, a11 = a00, a12 = a00, a13 = a00;
  for (int k0 = 0; k0 < K; k0 += 64) {
#pragma unroll
    for (int i = 0; i < 4; i++) {       // A tile: 128x64, 8 rows per inst
      int rb = (wv << 5) + (i << 3);
      gload16(Ag + (long)(rb + lrow) * K + k0 + lcol, &As[rb][0]);
    }
    if (fullW) {
#pragma unroll
      for (int i = 0; i < 2; i++) {     // W tile: 64x64
        int rb = (wv << 4) + (i << 3);
        gload16(Wg + (long)(rb + lrow) * K + k0 + lcol, &Ws[rb][0]);
      }
    } else {
      *(short8*)&Ws[wrow][wcol] = wok ? *(const short8*)(Wp + k0) : zz;
      *(short8*)&Ws[wrow][wcol + 8] = wok ? *(const short8*)(Wp + k0 + 8) : zz;
    }
    __syncthreads();
#pragma unroll
    for (int kk = 0; kk < 2; kk++) {
      int ko = (fq << 3) + (kk << 5);
      short8 af0 = *(const short8*)&As[(wv << 5) + fr][ko];
      short8 af1 = *(const short8*)&As[(wv << 5) + 16 + fr][ko];
      short8 b0 = *(const short8*)&Ws[fr][ko];
      short8 b1 = *(const short8*)&Ws[16 + fr][ko];
      short8 b2 = *(const short8*)&Ws[32 + fr][ko];
      short8 b3 = *(const short8*)&Ws[48 + fr][ko];
      a00 = __builtin_amdgcn_mfma_f32_16x16x32_bf16(af0, b0, a00, 0, 0, 0);
      a01 = __builtin_amdgcn_mfma_f32_16x16x32_bf16(af0, b1, a01, 0, 0, 0);
      a02 = __builtin_amdgcn_mfma_f32_16x16x32_bf16(af0, b2, a02, 0, 0, 0);
      a03 = __builtin_amdgcn_mfma_f32_16x16x32_bf16(af0, b3, a03, 0, 0, 0);
      a10 = __builtin_amdgcn_mfma_f32_16x16x32_bf16(af1, b0, a10, 0, 0, 0);
      a11 = __builtin_amdgcn_mfma_f32_16x16x32_bf16(af1, b1, a11, 0, 0, 0);
      a12 = __builtin_amdgcn_mfma_f32_16x16x32_bf16(af1, b2, a12, 0, 0, 0);
      a13 = __builtin_amdgcn_mfma_f32_16x16x32_bf16(af1, b3, a13, 0, 0, 0);
    }
    __syncthreads();
  }
  int ocol = n0 + fr;
  int orow0 = m0 + (wv << 5) + (fq << 2);
#define WRB(accv, mf, nt) { int col = ocol + ((nt) << 4); if (col < Nz) { \
    _Pragma("unroll") for (int r = 0; r < 4; r++) { \
      float vvv = accv[r]; if (col < actN) vvv = tanhf(vvv); \
      long oi = (long)(orow0 + ((mf) << 4) + r) * ldc + coff + col; \
      if (Cb) Cb[oi] = f2bf(vvv); else Cf[oi] = vvv; } } }
  WRB(a00, 0, 0) WRB(a01, 0, 1) WRB(a02, 0, 2) WRB(a03, 0, 3)
  WRB(a10, 1, 0) WRB(a11, 1, 1) WRB(a12, 1, 2) WRB(a13, 1, 3)
#undef WRB
}

// ---------------- deltas GEMM with fused mix-apply epilogue -----------------
// R13: same global_load_lds staging (all tiles full: M=2048, N=4096).
__global__ __launch_bounds__(256) void gemm_mixapply_kernel(
    const bf16* __restrict__ A, const bf16* __restrict__ W,
    const float* __restrict__ x, const float* __restrict__ tmaa,
    bf16* __restrict__ xrg, bf16* __restrict__ xwa,
    bf16* __restrict__ xk, bf16* __restrict__ xv) {
  __shared__ __align__(16) bf16 As[128][64];
  __shared__ __align__(16) bf16 Ws[64][64];
  const int K = 128;
  int n0 = blockIdx.x << 6;   // 0..4032
  int m0 = blockIdx.y << 7;
  int tid = threadIdx.x;
  int wv = tid >> 6, lane = tid & 63;
  int fr = lane & 15, fq = lane >> 4;
  int lrow = lane >> 3, lcol = (lane & 7) << 3;
  const bf16* Ag = A + (long)m0 * K;
  const bf16* Wg = W + (long)n0 * K;
  f32x4 a00 = {0.f, 0.f, 0.f, 0.f};
  f32x4 a01 = a00, a02 = a00, a03 = a00, a10 = a00, a11 = a00, a12 = a00, a13 = a00;
  for (int k0 = 0; k0 < K; k0 += 64) {
#pragma unroll
    for (int i = 0; i < 4; i++) {
      int rb = (wv << 5) + (i << 3);
      gload16(Ag + (long)(rb + lrow) * K + k0 + lcol, &As[rb][0]);
    }
#pragma unroll
    for (int i = 0; i < 2; i++) {
      int rb = (wv << 4) + (i << 3);
      gload16(Wg + (long)(rb + lrow) * K + k0 + lcol, &Ws[rb][0]);
    }
    __syncthreads();
#pragma unroll
    for (int kk = 0; kk < 2; kk++) {
      int ko = (fq << 3) + (kk << 5);
      short8 af0 = *(const short8*)&As[(wv << 5) + fr][ko];
      short8 af1 = *(const short8*)&As[(wv << 5) + 16 + fr][ko];
      short8 b0 = *(const short8*)&Ws[fr][ko];
      short8 b1 = *(const short8*)&Ws[16 + fr][ko];
      short8 b2 = *(const short8*)&Ws[32 + fr][ko];
      short8 b3 = *(const short8*)&Ws[48 + fr][ko];
      a00 = __builtin_amdgcn_mfma_f32_16x16x32_bf16(af0, b0, a00, 0, 0, 0);
      a01 = __builtin_amdgcn_mfma_f32_16x16x32_bf16(af0, b1, a01, 0, 0, 0);
      a02 = __builtin_amdgcn_mfma_f32_16x16x32_bf16(af0, b2, a02, 0, 0, 0);
      a03 = __builtin_amdgcn_mfma_f32_16x16x32_bf16(af0, b3, a03, 0, 0, 0);
      a10 = __builtin_amdgcn_mfma_f32_16x16x32_bf16(af1, b0, a10, 0, 0, 0);
      a11 = __builtin_amdgcn_mfma_f32_16x16x32_bf16(af1, b1, a11, 0, 0, 0);
      a12 = __builtin_amdgcn_mfma_f32_16x16x32_bf16(af1, b2, a12, 0, 0, 0);
      a13 = __builtin_amdgcn_mfma_f32_16x16x32_bf16(af1, b3, a13, 0, 0, 0);
    }
    __syncthreads();
  }
  int f = n0 >> 10;
  int c0 = n0 & 1023;
  bf16* outp = (f == 0) ? xrg : (f == 1) ? xwa : (f == 2) ? xk : xv;
  int ocol = c0 + fr;
  int orow0 = m0 + (wv << 5) + (fq << 2);
#define WRA(accv, mf, nt) { int cc = ocol + ((nt) << 4); \
    float ta = tmaa[(f << 10) + cc]; \
    _Pragma("unroll") for (int r = 0; r < 4; r++) { \
      int row = orow0 + ((mf) << 4) + r; \
      int t = row & (T_ - 1); \
      long xo = (long)row * C_ + cc; \
      float xb = x[xo]; \
      float xq = (t > 0) ? x[xo - C_] : 0.0f; \
      outp[xo] = f2bf(fmaf(xq - xb, ta + accv[r], xb)); } }
  WRA(a00, 0, 0) WRA(a01, 0, 1) WRA(a02, 0, 2) WRA(a03, 0, 3)
  WRA(a10, 1, 0) WRA(a11, 1, 1) WRA(a12, 1, 2) WRA(a13, 1, 3)
#undef WRA
}

// ---------------- K5: fuse2-lite (pure elementwise; dots via GEMM) ----------
__global__ __launch_bounds__(256) void fuse2_kernel(
    const float* __restrict__ kraw, const float* __restrict__ d2,
    const float* __restrict__ tdec, const float* __restrict__ taa,
    const float* __restrict__ tma, const float* __restrict__ tmk,
    float* __restrict__ ew, float* __restrict__ kfin,
    float* __restrict__ kkn, float* __restrict__ bbo) {
  int m = blockIdx.x, tid = threadIdx.x;
  int c4 = tid << 2;
  const float* dp = d2 + (long)m * 5120;
  float4 wd4 = *(const float4*)(dp + c4);
  float4 ad4 = *(const float4*)(dp + 1024 + c4);
  float4 mad4 = *(const float4*)(dp + 2048 + c4);
  float4 kd4 = *(const float4*)(dp + 3072 + c4);
  float4 mkd4 = *(const float4*)(dp + 4096 + c4);
  float4 kraw4 = *(const float4*)(kraw + (long)m * C_ + c4);
  float4 tdec4 = *(const float4*)(tdec + c4);
  float4 taa4 = *(const float4*)(taa + c4);
  float4 tma4 = *(const float4*)(tma + c4);
  float4 tmk4 = *(const float4*)(tmk + c4);
  float wd[4] = {wd4.x, wd4.y, wd4.z, wd4.w};
  float ad[4] = {ad4.x, ad4.y, ad4.z, ad4.w};
  float mad[4] = {mad4.x, mad4.y, mad4.z, mad4.w};
  float kd[4] = {kd4.x, kd4.y, kd4.z, kd4.w};
  float mkd[4] = {mkd4.x, mkd4.y, mkd4.z, mkd4.w};
  float krw[4] = {kraw4.x, kraw4.y, kraw4.z, kraw4.w};
  float td[4] = {tdec4.x, tdec4.y, tdec4.z, tdec4.w};
  float ta[4] = {taa4.x, taa4.y, taa4.z, taa4.w};
  float tm[4] = {tma4.x, tma4.y, tma4.z, tma4.w};
  float tk[4] = {tmk4.x, tmk4.y, tmk4.z, tmk4.w};
  float kkp[4], av[4], wvv[4], kr[4], mkv[4];
  float sumsq = 0.f;
#pragma unroll
  for (int j = 0; j < 4; j++) {
    float w = -softplusf_(-(td[j] + wd[j])) - 0.5f;
    wvv[j] = w;
    float kkpre = krw[j] + kd[j];
    kkp[j] = kkpre;
    sumsq += kkpre * kkpre;
    float a = sigmoidf_(ta[j] + ad[j]);
    av[j] = a;
    float ma = sigmoidf_(tm[j] + mad[j]);
    float mk = sigmoidf_(tk[j] + mkd[j]);
    mkv[j] = mk;
    kr[j] = krw[j] * (ma + a * (1.f - ma));
  }
  sumsq += __shfl_xor(sumsq, 1);
  sumsq += __shfl_xor(sumsq, 2);
  sumsq += __shfl_xor(sumsq, 4);
  sumsq += __shfl_xor(sumsq, 8);
  float rn = 1.0f / fmaxf(sqrtf(sumsq), 1e-12f);
  float4 kknv, bbov, eww, kfv;
  float* kknp = (float*)&kknv;
  float* bbop = (float*)&bbov;
  float* ewp = (float*)&eww;
  float* kfp = (float*)&kfv;
#pragma unroll
  for (int j = 0; j < 4; j++) {
    float kkx = kkp[j] * rn;
    kknp[j] = kkx;
    bbop[j] = -kkx * av[j];
    ewp[j] = expf(wvv[j]);
    kfp[j] = kr[j] * expf(wvv[j] * mkv[j]);
  }
  long off4 = (long)m * C_ + c4;
  *(float4*)(kkn + off4) = kknv;
  *(float4*)(bbo + off4) = bbov;
  *(float4*)(ew + off4) = eww;
  *(float4*)(kfin + off4) = kfv;
}

// ---------------- K6: RWKV-7 scan, 128 blocks x 256 threads -----------------
// R3 structure (dbuf LDS, 3-set rotating register pipeline, sched_barrier) +
// R7 y-pipeline. ~300 cyc/token sequential floor (T=1024 chain); resisted
// packing/scheduling/interleave; R11 fuse2-fold regressed 2.3x. Unchanged.
#define SCHUNK 16
#define NCHUNK (T_ / SCHUNK)
__global__ __launch_bounds__(256, 1) void scan_kernel(
    const float* __restrict__ rB, const float* __restrict__ ewB,
    const float* __restrict__ kB, const float* __restrict__ vB,
    const float* __restrict__ kkB, const float* __restrict__ bbB,
    float* __restrict__ yB) {
  __shared__ __align__(16) float lds[2][6][SCHUNK * 64];
  int bid = blockIdx.x;          // 0..127
  int bh = bid >> 2, rg = bid & 3;
  int b = bh >> 4, h = bh & 15;
  int tid = threadIdx.x;
  int wave = tid >> 6, lane = tid & 63;
  int g = lane >> 4, q = lane & 15;
  int row = (rg << 4) + (wave << 2) + g;
  int kq = q << 2;
  const long base = ((long)b * T_) * C_ + (h << 6);
  const float* s0 = kkB + base;
  const float* s1 = ewB + base;
  const float* s2 = kB + base;
  const float* s3 = bbB + base;
  const float* s4 = rB + base;
  const float* s5 = vB + base;
  int stok = tid >> 4;
  int spc = (tid & 15) << 2;
  int lo = (stok << 6) + spc;
  float4 rb0, rb1, rb2, rb3, rb4, rb5;
  auto loadc = [&](int c) {
    long go = (long)((c << 4) + stok) * C_ + spc;
    rb0 = *(const float4*)(s0 + go);
    rb1 = *(const float4*)(s1 + go);
    rb2 = *(const float4*)(s2 + go);
    rb3 = *(const float4*)(s3 + go);
    rb4 = *(const float4*)(s4 + go);
    rb5 = *(const float4*)(s5 + go);
  };
  auto stage = [&](int buf) {
    *(float4*)&lds[buf][0][lo] = rb0;
    *(float4*)&lds[buf][1][lo] = rb1;
    *(float4*)&lds[buf][2][lo] = rb2;
    *(float4*)&lds[buf][3][lo] = rb3;
    *(float4*)&lds[buf][4][lo] = rb4;
    *(float4*)&lds[buf][5][lo] = rb5;
  };
  float S0 = 0.f, S1 = 0.f, S2 = 0.f, S3 = 0.f;
  float ypv = 0.f;
  float4 Q0kk, Q0ew, Q0k, Q0bb, Q0r; float Q0v;
  float4 Q1kk, Q1ew, Q1k, Q1bb, Q1r; float Q1v;
  float4 Q2kk, Q2ew, Q2k, Q2bb, Q2r; float Q2v;

#define PF(i, tt) { int tb_ = ((tt) << 6); \
    Q##i##kk = *(const float4*)&lds[cur][0][tb_ + kq]; \
    Q##i##ew = *(const float4*)&lds[cur][1][tb_ + kq]; \
    Q##i##k  = *(const float4*)&lds[cur][2][tb_ + kq]; \
    Q##i##bb = *(const float4*)&lds[cur][3][tb_ + kq]; \
    Q##i##r  = *(const float4*)&lds[cur][4][tb_ + kq]; \
    Q##i##v  = lds[cur][5][tb_ + row]; }
#define SBAR __builtin_amdgcn_sched_barrier(0x7)
#define ST(i, gtok, FIRSTT) { \
    float p_ = fmaf(S1, Q##i##kk.y, S0 * Q##i##kk.x) + \
               fmaf(S3, Q##i##kk.w, S2 * Q##i##kk.z); \
    float yo_ = ypv; \
    qsum16x2(p_, yo_); \
    if (q == 0 && !((FIRSTT) && c == 0)) \
      yB[base + (long)((gtok) - 1) * C_ + row] = yo_; \
    float n0 = fmaf(S0, Q##i##ew.x, Q##i##v * Q##i##k.x); \
    float n1 = fmaf(S1, Q##i##ew.y, Q##i##v * Q##i##k.y); \
    float n2 = fmaf(S2, Q##i##ew.z, Q##i##v * Q##i##k.z); \
    float n3 = fmaf(S3, Q##i##ew.w, Q##i##v * Q##i##k.w); \
    S0 = fmaf(p_, Q##i##bb.x, n0); \
    S1 = fmaf(p_, Q##i##bb.y, n1); \
    S2 = fmaf(p_, Q##i##bb.z, n2); \
    S3 = fmaf(p_, Q##i##bb.w, n3); \
    ypv = fmaf(S1, Q##i##r.y, S0 * Q##i##r.x) + \
          fmaf(S3, Q##i##r.w, S2 * Q##i##r.z); }

  loadc(0);
  stage(0);
  loadc(1);
  __syncthreads();
  int cur = 0;
  for (int c = 0; c < NCHUNK; c++) {
    int t0 = c << 4;
    PF(0, 0); PF(1, 1);
    if (c + 1 < NCHUNK) stage(cur ^ 1);
    if (c + 2 < NCHUNK) loadc(c + 2);
    SBAR;
    PF(2, 2);  SBAR; ST(0, t0 + 0, true);
    PF(0, 3);  SBAR; ST(1, t0 + 1, false);
    PF(1, 4);  SBAR; ST(2, t0 + 2, false);
    PF(2, 5);  SBAR; ST(0, t0 + 3, false);
    PF(0, 6);  SBAR; ST(1, t0 + 4, false);
    PF(1, 7);  SBAR; ST(2, t0 + 5, false);
    PF(2, 8);  SBAR; ST(0, t0 + 6, false);
    PF(0, 9);  SBAR; ST(1, t0 + 7, false);
    PF(1, 10); SBAR; ST(2, t0 + 8, false);
    PF(2, 11); SBAR; ST(0, t0 + 9, false);
    PF(0, 12); SBAR; ST(1, t0 + 10, false);
    PF(1, 13); SBAR; ST(2, t0 + 11, false);
    PF(2, 14); SBAR; ST(0, t0 + 12, false);
    PF(0, 15); SBAR; ST(1, t0 + 13, false);
    ST(2, t0 + 14, false);
    ST(0, t0 + 15, false);
    __syncthreads();
    cur ^= 1;
  }
  {
    float yo = qsum16(ypv);
    if (q == 0) yB[base + (long)(T_ - 1) * C_ + row] = yo;
  }
#undef PF
#undef SBAR
#undef ST
}

// ---------------- K7: GroupNorm + bonus + gate (bf16 out) -------------------
__global__ __launch_bounds__(256) void gnout_kernel(
    const float* __restrict__ y, const float* __restrict__ r,
    const float* __restrict__ kf, const float* __restrict__ v,
    const float* __restrict__ g,
    const float* __restrict__ lnw, const float* __restrict__ lnb,
    const float* __restrict__ fa, bf16* __restrict__ z) {
  int tid = threadIdx.x;
  int w = tid >> 6, lane = tid & 63;
  int gi = (blockIdx.x << 2) + w;
  int h = gi & 15, mt = gi >> 4;
  long off = (long)mt * C_ + (h << 6) + lane;
  float yv = y[off];
  float s = yv;
  s += __shfl_xor(s, 1); s += __shfl_xor(s, 2); s += __shfl_xor(s, 4);
  s += __shfl_xor(s, 8); s += __shfl_xor(s, 16); s += __shfl_xor(s, 32);
  float mu = s * (1.0f / 64.0f);
  float d = yv - mu;
  float s2 = d * d;
  s2 += __shfl_xor(s2, 1); s2 += __shfl_xor(s2, 2); s2 += __shfl_xor(s2, 4);
  s2 += __shfl_xor(s2, 8); s2 += __shfl_xor(s2, 16); s2 += __shfl_xor(s2, 32);
  float var = s2 * (1.0f / 64.0f);
  int hc = (h << 6) + lane;
  float dot = r[off] * kf[off] * fa[hc];
  dot += __shfl_xor(dot, 1); dot += __shfl_xor(dot, 2); dot += __shfl_xor(dot, 4);
  dot += __shfl_xor(dot, 8); dot += __shfl_xor(dot, 16); dot += __shfl_xor(dot, 32);
  float yn = d * rsqrtf(var + 0.00064f) * lnw[hc] + lnb[hc];
  z[off] = f2bf((yn + dot * v[off]) * g[off]);
}

extern "C" void kernel_launch(void* const* d_in, const int* in_sizes, int n_in,
                              void* d_out, int out_size, void* d_ws, size_t ws_size,
                              hipStream_t stream) {
  const float* x = (const float*)d_in[0];
  const float* tmx = (const float*)d_in[1];
  const float* tmaa = (const float*)d_in[2];
  const float* tmw1 = (const float*)d_in[3];
  const float* tmw2 = (const float*)d_in[4];
  const float* tdec = (const float*)d_in[5];
  const float* tdw1 = (const float*)d_in[6];
  const float* tdw2 = (const float*)d_in[7];
  const float* taa5 = (const float*)d_in[8];
  const float* taw1 = (const float*)d_in[9];
  const float* taw2 = (const float*)d_in[10];
  const float* tkw1 = (const float*)d_in[11];
  const float* tkw2 = (const float*)d_in[12];
  const float* gw1 = (const float*)d_in[13];
  const float* gw2 = (const float*)d_in[14];
  const float* tmia = (const float*)d_in[15];
  const float* maw1 = (const float*)d_in[16];
  const float* maw2 = (const float*)d_in[17];
  const float* tmik = (const float*)d_in[18];
  const float* mkw1 = (const float*)d_in[19];
  const float* mkw2 = (const float*)d_in[20];
  const float* wrec = (const float*)d_in[21];
  const float* wkey = (const float*)d_in[22];
  const float* wval = (const float*)d_in[23];
  const float* wout = (const float*)d_in[24];
  const float* lnw = (const float*)d_in[25];
  const float* lnb = (const float*)d_in[26];
  const float* faaa = (const float*)d_in[27];

  const long MT = 2048, CC = 1024;
  char* base = (char*)d_ws;
  float* y = (float*)base;     base += MT * CC * 4;
  bf16* xrgb = (bf16*)base;    base += MT * CC * 2;   // ┐ kfin overlays (8MB)
  bf16* xwab = (bf16*)base;    base += MT * CC * 2;   // ┘
  bf16* xkb = (bf16*)base;     base += MT * CC * 2;   // ┐ kkn overlays (8MB)
  bf16* xvb = (bf16*)base;     base += MT * CC * 2;   // ┘
  float* rr = (float*)base;    base += MT * CC * 4;
  float* kraw = (float*)base;  base += MT * CC * 4;   // also ew
  float* vv = (float*)base;    base += MT * CC * 4;
  float* gg = (float*)base;    base += MT * CC * 4;
  float* bbo = (float*)base;   base += MT * CC * 4;
  bf16* g1b = (bf16*)base;     base += MT * 128 * 2;
  bf16* out12b = (bf16*)base;  base += MT * 128 * 2;  // [w1|a1|ma1|kk1|mk1]
  bf16* zb = (bf16*)base;      base += MT * CC * 2;
  bf16* mixb = (bf16*)base;    base += MT * 128 * 2;
  float* d2 = (float*)base;    base += MT * 5120L * 4; // fuse2 dots (fp32)
  bf16* tmw1b = (bf16*)base;   base += 128 * CC * 2;
  bf16* wrecb = (bf16*)base;   base += CC * CC * 2;
  bf16* gw1b = (bf16*)base;    base += 128 * CC * 2;
  bf16* gw2b = (bf16*)base;    base += CC * 128 * 2;
  bf16* wkeyb = (bf16*)base;   base += CC * CC * 2;
  bf16* wvalb = (bf16*)base;   base += CC * CC * 2;
  bf16* woutb = (bf16*)base;   base += CC * CC * 2;
  bf16* wskb = (bf16*)base;    base += 32 * CC * 2;
  bf16* wswab = (bf16*)base;   base += 96 * CC * 2;
  bf16* tmw2e = (bf16*)base;   base += 4096L * 128 * 2;
  bf16* w2e5b = (bf16*)base;   base += 5120L * 128 * 2;
  // aliases (dead-buffer reuse, verified non-overlapping in time):
  float* ew = kraw;            // fuse2 reads kraw then writes ew at same offs
  float* kfin = (float*)xrgb;  // xrg/xwa bf16 dead before fuse2
  float* kkn = (float*)xkb;    // xk/xv bf16 dead before fuse2

  // one launch: all conversions/expansions + the mix GEMM (raw-f32 W staging)
  cvt_mix_kernel<<<5792, 256, 0, stream>>>(
      tmw1, wrec, gw1, gw2, wkey, wval, wout,
      tmw1b, wrecb, gw1b, gw2b, wkeyb, wvalb, woutb,
      tkw1, mkw1, tdw1, taw1, maw1, wskb, wswab,
      tmw2, tdw2, tkw2, taw2, maw2, mkw2,
      tmw2e, w2e5b, x, tmx, mixb);

  // deltas GEMM with fused mix-apply epilogue -> xrg/xwa/xk/xv
  gemm_mixapply_kernel<<<dim3(64, 16), 256, 0, stream>>>(
      mixb, tmw2e, x, tmaa, xrgb, xwab, xkb, xvb);
  // 6 independent K=1024 GEMMs, one launch; z=3/z=5 write slices of out12b
  {
    GemmBatch gb = {};
    gb.A[0] = xrgb; gb.W[0] = wrecb; gb.Cf[0] = rr;      gb.Cb[0] = nullptr; gb.N[0] = 1024; gb.actN[0] = 0;   gb.ldc[0] = 1024; gb.coff[0] = 0;
    gb.A[1] = xrgb; gb.W[1] = gw1b;  gb.Cf[1] = nullptr; gb.Cb[1] = g1b;     gb.N[1] = 128;  gb.actN[1] = 128; gb.ldc[1] = 128;  gb.coff[1] = 0;
    gb.A[2] = xkb;  gb.W[2] = wkeyb; gb.Cf[2] = kraw;    gb.Cb[2] = nullptr; gb.N[2] = 1024; gb.actN[2] = 0;   gb.ldc[2] = 1024; gb.coff[2] = 0;
    gb.A[3] = xkb;  gb.W[3] = wskb;  gb.Cf[3] = nullptr; gb.Cb[3] = out12b;  gb.N[3] = 32;   gb.actN[3] = 16;  gb.ldc[3] = 128;  gb.coff[3] = 96;
    gb.A[4] = xvb;  gb.W[4] = wvalb; gb.Cf[4] = vv;      gb.Cb[4] = nullptr; gb.N[4] = 1024; gb.actN[4] = 0;   gb.ldc[4] = 1024; gb.coff[4] = 0;
    gb.A[5] = xwab; gb.W[5] = wswab; gb.Cf[5] = nullptr; gb.Cb[5] = out12b;  gb.N[5] = 96;   gb.actN[5] = 64;  gb.ldc[5] = 128;  gb.coff[5] = 0;
    gemm_batch_kernel<<<dim3(16, 16, 6), 256, 0, stream>>>(gb, 1024);
  }
  // batch2 (K=128): gg GEMM + fuse2-dots GEMM (d2 = out12b x w2e5^T, fp32)
  {
    GemmBatch gb = {};
    gb.A[0] = g1b;    gb.W[0] = gw2b;  gb.Cf[0] = gg; gb.Cb[0] = nullptr; gb.N[0] = 1024; gb.actN[0] = 0; gb.ldc[0] = 1024; gb.coff[0] = 0;
    gb.A[1] = out12b; gb.W[1] = w2e5b; gb.Cf[1] = d2; gb.Cb[1] = nullptr; gb.N[1] = 5120; gb.actN[1] = 0; gb.ldc[1] = 5120; gb.coff[1] = 0;
    gemm_batch_kernel<<<dim3(80, 16, 2), 256, 0, stream>>>(gb, 128);
  }
  fuse2_kernel<<<2048, 256, 0, stream>>>(kraw, d2, tdec, taa5, tmia, tmik,
                                         ew, kfin, kkn, bbo);
  scan_kernel<<<128, 256, 0, stream>>>(rr, ew, kfin, vv, kkn, bbo, y);
  gnout_kernel<<<8192, 256, 0, stream>>>(y, rr, kfin, vv, gg, lnw, lnb, faaa, zb);
  // output GEMM: (2048x1024)x(1024x1024)^T
  {
    GemmBatch gb = {};
    gb.A[0] = zb; gb.W[0] = woutb; gb.Cf[0] = (float*)d_out; gb.Cb[0] = nullptr;
    gb.N[0] = 1024; gb.actN[0] = 0; gb.ldc[0] = 1024; gb.coff[0] = 0;
    gemm_batch_kernel<<<dim3(16, 16, 1), 256, 0, stream>>>(gb, 1024);
  }
}